// Round 16
// baseline (344.666 us; speedup 1.0000x reference)
//
#include <hip/hip_runtime.h>

#define CH    64
#define NTOK  2049
#define NTOKP 2064
#define MROWS 4098
#define NCJ   3

typedef __attribute__((ext_vector_type(8))) short bf16x8;
typedef __attribute__((ext_vector_type(4))) float f32x4;
typedef __attribute__((ext_vector_type(2))) int i32x2;

// workspace offsets (float units)
#define OFF_X     0u
#define OFF_XNB   524544u
#define OFF_RTB   786816u
#define OFF_RCB   1049088u
#define OFF_QKVB  1311360u
#define OFF_KTCB  4458624u
#define OFF_KSB   6556800u
#define OFF_VTB   8662656u
#define OFF_COLB  9727616u
#define OFF_WT    9760640u
#define OFF_OP    10284928u
#define OFF_ATTNO 13432192u
#define OFF_FFNH  14481280u

// 0.125 * log2(e): folds SCALE and exp->exp2 conversion into ksum/colb pre-scale
#define QSCALE 0.1803368801111204f

#define GLOAD_LDS16(gp, lp) __builtin_amdgcn_global_load_lds( \
    (const __attribute__((address_space(1))) void*)(gp), \
    (__attribute__((address_space(3))) void*)(lp), 16, 0, 0)

__device__ __forceinline__ float wave_allreduce_sum(float v) {
    #pragma unroll
    for (int m = 1; m < 64; m <<= 1) v += __shfl_xor(v, m);
    return v;
}

__device__ __forceinline__ ushort bf16rnd(float x) {
    unsigned u = __builtin_bit_cast(unsigned, x);
    u += 0x7FFF + ((u >> 16) & 1);
    return (ushort)(u >> 16);
}

__device__ __forceinline__ float bf16tof(ushort u) {
    return __builtin_bit_cast(float, ((unsigned)u) << 16);
}

// ---------------- weight prep: f32 [K][N] -> bf16 Wt [N][K] (ktc concatenated) ----------------
__global__ __launch_bounds__(256) void wprep_kernel(
    const float* __restrict__ wqkv, const float* __restrict__ wkt, const float* __restrict__ wkc,
    const float* __restrict__ wo, const float* __restrict__ w1, const float* __restrict__ w2,
    ushort* __restrict__ wT)
{
    int l = blockIdx.z, mat = blockIdx.y;
    int idx = blockIdx.x * 256 + threadIdx.x;
    float v; int off;
    if (mat == 0) {            // qkv: N=1536 K=128
        if (idx >= 196608) return;
        int n = idx >> 7, k = idx & 127;
        v = wqkv[(size_t)l * 196608 + (size_t)k * 1536 + n]; off = 0;
    } else if (mat == 1) {     // ktc: N=512 K=256 (wkt | wkc)
        if (idx >= 131072) return;
        int n = idx >> 8, k = idx & 255;
        v = (k < 128) ? wkt[(size_t)l * 65536 + (size_t)k * 512 + n]
                      : wkc[(size_t)l * 65536 + (size_t)(k - 128) * 512 + n];
        off = 196608;
    } else if (mat == 2) {     // wo: N=128 K=512
        if (idx >= 65536) return;
        int n = idx >> 9, k = idx & 511;
        v = wo[(size_t)l * 65536 + (size_t)k * 128 + n]; off = 327680;
    } else if (mat == 3) {     // w1: N=512 K=128
        if (idx >= 65536) return;
        int n = idx >> 7, k = idx & 127;
        v = w1[(size_t)l * 65536 + (size_t)k * 512 + n]; off = 393216;
    } else {                   // w2: N=128 K=512
        if (idx >= 65536) return;
        int n = idx >> 9, k = idx & 511;
        v = w2[(size_t)l * 65536 + (size_t)k * 128 + n]; off = 458752;
    }
    wT[(size_t)l * 524288 + off + idx] = bf16rnd(v);
}

// ---------------- embed ----------------
__global__ __launch_bounds__(128) void embed_kernel(
    const float* __restrict__ eeg, const float* __restrict__ est, const int* __restrict__ cvi,
    const float* __restrict__ cw, const float* __restrict__ cb,
    const float* __restrict__ cls, const float* __restrict__ clsp,
    float* __restrict__ x, ushort* __restrict__ rt, ushort* __restrict__ rc)
{
    int id = blockIdx.x;
    int d = threadIdx.x;
    if (id >= 4096) {
        int b = id - 4096;
        size_t base = (size_t)b * NTOK * 128 + d;
        x[base]  = cls[d];
        rt[base] = bf16rnd(clsp[d]);
        rc[base] = bf16rnd(clsp[d]);
        return;
    }
    int b = id >> 11, rem = id & 2047, c = rem >> 5, w = rem & 31;
    __shared__ float xs[25];
    if (d < 25) xs[d] = eeg[((size_t)(b * CH + c)) * 800 + w * 25 + d];
    __syncthreads();
    float acc = cb[d];
    #pragma unroll
    for (int p = 0; p < 25; ++p) acc += xs[p] * cw[d * 25 + p];
    int i = 1 + c * 32 + w;
    size_t base = ((size_t)b * NTOK + i) * 128 + d;
    x[base] = acc;
    int k = d & 63;
    float invk = __expf(-0.14391156831f * (float)k);
    float pt = floorf(est[b] / 0.1f) + (float)w;
    float at = pt * invk;
    rt[base] = bf16rnd((d < 64) ? sinf(at) : cosf(at));
    float pc = (float)cvi[b * CH + c];
    float ac = pc * invk;
    rc[base] = bf16rnd((d < 64) ? sinf(ac) : cosf(ac));
}

// ---------------- layernorm, bf16 out ----------------
__global__ __launch_bounds__(256) void ln_kernel(
    const float* __restrict__ x, const float* __restrict__ g, const float* __restrict__ bb,
    ushort* __restrict__ out, int rows)
{
    int w = threadIdx.x >> 6, lane = threadIdx.x & 63;
    int row = blockIdx.x * 4 + w;
    if (row >= rows) return;
    const float* xr = x + (size_t)row * 128;
    float v0 = xr[lane], v1 = xr[lane + 64];
    float mean = wave_allreduce_sum(v0 + v1) * (1.0f / 128.0f);
    float d0 = v0 - mean, d1 = v1 - mean;
    float var = wave_allreduce_sum(d0 * d0 + d1 * d1) * (1.0f / 128.0f);
    float inv = rsqrtf(var + 1e-5f);
    out[(size_t)row * 128 + lane]      = bf16rnd(d0 * inv * g[lane]      + bb[lane]);
    out[(size_t)row * 128 + lane + 64] = bf16rnd(d1 * inv * g[lane + 64] + bb[lane + 64]);
}

// ---------------- bf16 MFMA GEMM: C = A[MxK] * Wt[NxK]; A may be [A | A2] concat on K ----------------
// mode: 2 -> outB = bf16(gelu(acc+bias)); 3 -> outB = bf16(acc)
__global__ __launch_bounds__(256, 3) void mgemm_kernel(
    const ushort* __restrict__ A, const ushort* __restrict__ A2, int K1,
    const ushort* __restrict__ Wt,
    float* outF, ushort* outB, const float* bias, const float* res,
    int M, int K, int N, int mode)
{
    __shared__ ushort Alds[128 * 72];
    __shared__ ushort Blds[128 * 72];
    int tid = threadIdx.x;
    int lane = tid & 63, wv = tid >> 6;
    int wm = wv >> 1, wn = wv & 1;
    int li = lane & 15, g = lane >> 4;
    int m0 = blockIdx.y * 128, n0 = blockIdx.x * 128;
    int K2s = K - K1;
    f32x4 acc[4][4];
    #pragma unroll
    for (int a = 0; a < 4; ++a)
        #pragma unroll
        for (int c = 0; c < 4; ++c) acc[a][c] = (f32x4){0.f, 0.f, 0.f, 0.f};

    for (int kb = 0; kb < K; kb += 64) {
        #pragma unroll
        for (int it = 0; it < 4; ++it) {
            int gi = tid + it * 256;
            int row = gi >> 3, gc = gi & 7;
            int m = m0 + row; if (m >= M) m = M - 1;
            int acol = kb + gc * 8;
            const ushort* asrc = (acol < K1) ? (A + (size_t)m * K1 + acol)
                                             : (A2 + (size_t)m * K2s + (acol - K1));
            bf16x8 av = *(const bf16x8*)asrc;
            *(bf16x8*)&Alds[row * 72 + ((gc ^ (row & 7)) << 3)] = av;
            int n = n0 + row;
            bf16x8 bv = *(const bf16x8*)(Wt + (size_t)n * K + acol);
            *(bf16x8*)&Blds[row * 72 + ((gc ^ (row & 7)) << 3)] = bv;
        }
        __syncthreads();
        #pragma unroll
        for (int k2 = 0; k2 < 2; ++k2) {
            bf16x8 af[4], bfr[4];
            #pragma unroll
            for (int xx = 0; xx < 4; ++xx) {
                int ra = wm * 64 + xx * 16 + li;
                int rb = wn * 64 + xx * 16 + li;
                af[xx]  = *(const bf16x8*)&Alds[ra * 72 + (((k2 * 4 + g) ^ (ra & 7)) << 3)];
                bfr[xx] = *(const bf16x8*)&Blds[rb * 72 + (((k2 * 4 + g) ^ (rb & 7)) << 3)];
            }
            #pragma unroll
            for (int mi = 0; mi < 4; ++mi)
                #pragma unroll
                for (int ni = 0; ni < 4; ++ni)
                    acc[mi][ni] = __builtin_amdgcn_mfma_f32_16x16x32_bf16(af[mi], bfr[ni], acc[mi][ni], 0, 0, 0);
        }
        __syncthreads();
    }
    #pragma unroll
    for (int mi = 0; mi < 4; ++mi) {
        #pragma unroll
        for (int r = 0; r < 4; ++r) {
            int m = m0 + wm * 64 + mi * 16 + 4 * g + r;
            if (m >= M) continue;
            #pragma unroll
            for (int ni = 0; ni < 4; ++ni) {
                int n = n0 + wn * 64 + ni * 16 + li;
                float v = acc[mi][ni][r];
                if (mode == 2) {
                    v += bias[n];
                    v = 0.5f * v * (1.0f + erff(v * 0.70710678118f));
                    outB[(size_t)m * N + n] = bf16rnd(v);
                } else {
                    outB[(size_t)m * N + n] = bf16rnd(v);
                }
            }
        }
    }
}

// ---------------- thin GEMM (N=128, K=512): one 16x16 tile per wave, no LDS ----------------
__global__ __launch_bounds__(256) void tgemm_kernel(
    const ushort* __restrict__ A, const ushort* __restrict__ Wt,
    float* __restrict__ outF, const float* __restrict__ bias, const float* __restrict__ res,
    int M, int N)
{
    int lane = threadIdx.x & 63, wv = threadIdx.x >> 6;
    int li = lane & 15, g = lane >> 4;
    int mt = blockIdx.y * 4 + wv;
    int m0 = mt * 16, n0 = blockIdx.x * 16;
    int ar = m0 + li; if (ar >= M) ar = M - 1;
    const ushort* arow = A + (size_t)ar * 512 + 8 * g;
    const ushort* brow = Wt + (size_t)(n0 + li) * 512 + 8 * g;
    f32x4 acc = (f32x4){0.f, 0.f, 0.f, 0.f};
    #pragma unroll
    for (int k2 = 0; k2 < 16; ++k2) {
        bf16x8 af = *(const bf16x8*)(arow + k2 * 32);
        bf16x8 bf = *(const bf16x8*)(brow + k2 * 32);
        acc = __builtin_amdgcn_mfma_f32_16x16x32_bf16(af, bf, acc, 0, 0, 0);
    }
    #pragma unroll
    for (int r = 0; r < 4; ++r) {
        int m = m0 + 4 * g + r;
        if (m < M) {
            int n = n0 + li;
            outF[(size_t)m * N + n] = acc[r] + bias[n] + res[(size_t)m * N + n];
        }
    }
}

// ---------------- remap -> ksum(xQSCALE, padded) + colb(padded); zeroes pad rows ----------------
// qn/vn intermediates eliminated: attn reads Q and vtrans reads V directly from qkvb
// via the inverse index map (round-16 change). QSCALE moved from q to ksum (equivalent).
__global__ __launch_bounds__(512) void remap_kernel(
    const ushort* __restrict__ qkvb, const ushort* __restrict__ ktcb,
    const float* __restrict__ bte, const float* __restrict__ btr,
    const float* __restrict__ bcr, const float* __restrict__ bce,
    ushort* __restrict__ ksum, float* __restrict__ colb)
{
    int id = blockIdx.x;            // b2*NTOK + i2, or pad block
    int t = threadIdx.x;
    if (id >= MROWS) {              // zero pad rows j in [2049,2064) of ksum/colb
        int pidx = id - MROWS;
        int b2 = pidx / 15, i2 = 2049 + pidx % 15;
        ksum[((size_t)(b2 * NTOKP + i2)) * 512 + t] = 0;
        if (t < 8) colb[((size_t)(b2 * NTOKP + i2)) * 8 + t] = 0.0f;
        return;
    }
    int b2 = id / NTOK, i2 = id - b2 * NTOK;
    int h2 = t >> 6, d2 = t & 63;
    int G = i2 * 16 + b2 * 8 + h2;
    int bhA = G / 2049, iA = G - bhA * 2049;
    int bA = bhA >> 3, hA = bhA & 7;
    size_t qbase = ((size_t)(bA * NTOK + iA)) * 1536 + hA * 64 + d2;
    ushort kvu = qkvb[qbase + 512];
    int bB = G / 16392, remB = G - bB * 16392;
    int iB = remB >> 3, hB = remB & 7;
    ushort ktcu = ktcb[((size_t)(bB * NTOK + iB)) * 512 + hB * 64 + d2];
    float kv = bf16tof(kvu), ktcv = bf16tof(ktcu);
    ksum[((size_t)(b2 * NTOKP + i2)) * 512 + t] = bf16rnd((kv + ktcv) * QSCALE);
    float cbx = (bte[t] + bce[t]) * kv + (btr[t] + bcr[t]) * ktcv;
    cbx = wave_allreduce_sum(cbx);
    if (d2 == 0) colb[((size_t)(b2 * NTOKP + i2)) * 8 + h2] = cbx;
}

// ---------------- transpose V: qkvb (old space, inverse map) -> vt[b][d][j 2080] ----------------
__global__ __launch_bounds__(256) void vtrans_kernel(
    const ushort* __restrict__ qkvb, ushort* __restrict__ vt)
{
    __shared__ ushort tile[32][36];
    int jt = blockIdx.x, dt = blockIdx.y, b = blockIdx.z;
    int t = threadIdx.x;
    {
        int jj = t >> 3, dq = t & 7;
        int j = jt * 32 + jj;
        ushort4 v = make_ushort4(0, 0, 0, 0);
        if (j <= 2048) {
            int h2 = dt >> 1;
            int d2 = (dt & 1) * 32 + dq * 4;
            int G = j * 16 + b * 8 + h2;
            int bhA = G / 2049, iA = G - bhA * 2049;
            int bA = bhA >> 3, hA = bhA & 7;
            v = *(const ushort4*)(qkvb + ((size_t)(bA * NTOK + iA)) * 1536 + 1024 + hA * 64 + d2);
        }
        *(ushort4*)&tile[jj][dq * 4] = v;
    }
    __syncthreads();
    {
        int dd = t >> 3, jq = t & 7;
        ushort4 w;
        w.x = tile[jq * 4 + 0][dd];
        w.y = tile[jq * 4 + 1][dd];
        w.z = tile[jq * 4 + 2][dd];
        w.w = tile[jq * 4 + 3][dd];
        *(ushort4*)(vt + ((size_t)b * 512 + dt * 32 + dd) * 2080 + jt * 32 + jq * 4) = w;
    }
}

// ---------------- attn9: swapped-QK, heads split across wave pair + LDS sum-exchange ----------------
// Best-measured structure (85 us/layer). grid (65, NCJ=3, 2) = 390 blocks, 2 blocks/CU.
// Everything double-buffered; K/V/cb staged post-B2 (one full iteration of prefetch distance).
// Q fragments gathered directly from qkvb via inverse map (qn eliminated; scale folded in ksum).
// LDS: K dbuf 2x16K @0 | V dbuf 2x16K @32768 | cb dbuf 2x768 @65536 | ex 4K @67072 = 69.4KB.
__global__ __launch_bounds__(256, 2) void attn9_kernel(
    const ushort* __restrict__ qkvb, const ushort* __restrict__ ks,
    const ushort* __restrict__ vt, const float* __restrict__ colb,
    ushort* __restrict__ Op)
{
    __shared__ __align__(16) char smem[71168];
    const int tid = threadIdx.x;
    const int lane = tid & 63, wv = tid >> 6;
    const int wi = wv >> 1, hg = wv & 1;
    const int g = lane >> 4, li = lane & 15;
    const int nc = blockIdx.y, b = blockIdx.z;
    const int i0 = blockIdx.x * 32;
    const int jt0 = nc * 43, jt1 = (nc + 1) * 43;

    // Q fragments: own 4 heads x 2 k2, gathered from qkvb (old space) via inverse map
    bf16x8 qf[4][2];
    {
        int iq = i0 + wi * 16 + li; if (iq > 2048) iq = 2048;
        #pragma unroll
        for (int hh = 0; hh < 4; ++hh) {
            int h2 = hg * 4 + hh;
            int G = iq * 16 + b * 8 + h2;
            int bhA = G / 2049, iA = G - bhA * 2049;
            int bA = bhA >> 3, hA = bhA & 7;
            const ushort* qrow = qkvb + ((size_t)(bA * NTOK + iA)) * 1536 + hA * 64 + 8 * g;
            qf[hh][0] = *(const bf16x8*)(qrow);
            qf[hh][1] = *(const bf16x8*)(qrow + 32);
        }
    }
    f32x4 o[4][4];   // own 4 heads x 4 d-subtiles -> AGPR
    #pragma unroll
    for (int a = 0; a < 4; ++a)
        #pragma unroll
        for (int m = 0; m < 4; ++m) o[a][m] = (f32x4){0.f, 0.f, 0.f, 0.f};

    // hoisted per-lane LDS read bases
    const unsigned koff0 = (unsigned)(li * 1024) + (unsigned)((g * 16) ^ ((li & 7) << 4))
                         + (unsigned)(hg * 512);
    const unsigned koff1 = (unsigned)(li * 1024) + (unsigned)((64 + g * 16) ^ ((li & 7) << 4))
                         + (unsigned)(hg * 512);
    const unsigned vboff = (unsigned)(li * 32)
                         + (unsigned)((((g >> 1) ^ ((li >> 2) & 1)) << 4) + (g & 1) * 8)
                         + (unsigned)(hg * 8192);
    const unsigned exoff = 67072u + (unsigned)(wv * 1024 + lane * 16);
    const unsigned exoffp = 67072u + (unsigned)((wv ^ 1) * 1024 + lane * 16);

    // staging (padded buffers: NO clamps, affine in jt)
    const ushort* ksb_b = ks + ((size_t)b * NTOKP) * 512;
    auto stageK = [&](int jt, int buf) {
        #pragma unroll
        for (int t = 0; t < 4; ++t) {
            unsigned L = (unsigned)((wv * 256 + t * 64 + lane) * 16);
            unsigned Lp = L ^ (((L >> 10) & 7u) << 4);
            const ushort* src = ksb_b + (size_t)(jt * 16 + (int)(Lp >> 10)) * 512 + ((Lp & 1023u) >> 1);
            GLOAD_LDS16(src, smem + buf * 16384 + (wv * 256 + t * 64) * 16);
        }
    };
    const ushort* vtb_b = vt + (size_t)b * 512 * 2080;
    auto stageV = [&](int jt, int buf) {
        #pragma unroll
        for (int t = 0; t < 4; ++t) {
            int n = wv * 256 + t * 64 + lane;
            int d = n >> 1;
            int h16 = (n & 1) ^ ((n >> 3) & 1);
            const ushort* src = vtb_b + (size_t)d * 2080 + jt * 16 + h16 * 8;
            GLOAD_LDS16(src, smem + 32768 + buf * 16384 + (wv * 256 + t * 64) * 16);
        }
    };
    auto loadcb = [&](int jt) -> float {
        if (tid < 128) {
            int jg = jt * 16 + (tid >> 3);
            if (jg > 2063) jg = 2063;      // pad rows are zero; just keep in-bounds
            return colb[((size_t)(b * NTOKP + jg)) * 8 + (tid & 7)] * QSCALE;
        }
        return 0.f;
    };

    stageK(jt0, 0); stageV(jt0, 0);
    {
        float c0 = loadcb(jt0);
        if (tid < 128) ((float*)(smem + 65536))[(tid >> 3) * 12 + (tid & 7)] = c0;
    }
    float cbreg = loadcb(jt0 + 1);

    int cur = 0;
    for (int jt = jt0; jt < jt1; ++jt) {
        __syncthreads();   // B1: staging(jt)+cb(jt) visible; prev ex reads done
        // ---- QK (swapped): s[hh](j=4g+r, i=li), own 4 heads only ----
        const char* kb = smem + cur * 16384;
        f32x4 s[4];
        #pragma unroll
        for (int hh = 0; hh < 4; ++hh) {
            s[hh] = (f32x4){0.f, 0.f, 0.f, 0.f};
            bf16x8 kf0 = *(const bf16x8*)(kb + koff0 + hh * 128);
            s[hh] = __builtin_amdgcn_mfma_f32_16x16x32_bf16(kf0, qf[hh][0], s[hh], 0, 0, 0);
            bf16x8 kf1 = *(const bf16x8*)(kb + koff1 + hh * 128);
            s[hh] = __builtin_amdgcn_mfma_f32_16x16x32_bf16(kf1, qf[hh][1], s[hh], 0, 0, 0);
        }
        // ---- exp2 own heads + partial head-sum -> LDS exchange ----
        const float* cbl = (const float*)(smem + 65536 + cur * 768);
        float p[4][4];
        #pragma unroll
        for (int rp = 0; rp < 2; ++rp) {
            f32x4 ce = *(const f32x4*)(cbl + (4 * g + 2 * rp) * 12 + hg * 4);
            f32x4 co = *(const f32x4*)(cbl + (4 * g + 2 * rp) * 12 + 12 + hg * 4);
            #pragma unroll
            for (int hh = 0; hh < 4; ++hh) {
                p[hh][2 * rp]     = __builtin_amdgcn_exp2f(s[hh][2 * rp]     + ce[hh]);
                p[hh][2 * rp + 1] = __builtin_amdgcn_exp2f(s[hh][2 * rp + 1] + co[hh]);
            }
        }
        f32x4 e;
        #pragma unroll
        for (int r = 0; r < 4; ++r)
            e[r] = (p[0][r] + p[1][r]) + (p[2][r] + p[3][r]);
        *(f32x4*)(smem + exoff) = e;
        __syncthreads();   // B2: exchange visible (staging(jt) long drained)
        f32x4 eo = *(const f32x4*)(smem + exoffp);
        // ---- issue next-tile staging + cb write NOW (post-B2: latency spans PV + next QK) ----
        const bool hn = (jt + 1 < jt1);
        if (hn) {
            if (tid < 128) ((float*)(smem + 65536 + (cur ^ 1) * 768))[(tid >> 3) * 12 + (tid & 7)] = cbreg;
            stageK(jt + 1, cur ^ 1);
            stageV(jt + 1, cur ^ 1);
            cbreg = loadcb(jt + 2);
        }
        // ---- full softmax denominator, pack P (PV A-operand) ----
        float inv[4];
        #pragma unroll
        for (int r = 0; r < 4; ++r)
            inv[r] = __builtin_amdgcn_rcpf(fmaxf(e[r] + eo[r], 1e-20f));  // NORMAL floor
        unsigned P2[4][2];
        #pragma unroll
        for (int hh = 0; hh < 4; ++hh)
            #pragma unroll
            for (int rp = 0; rp < 2; ++rp) {
                float lo = p[hh][2 * rp] * inv[2 * rp];
                float hi = p[hh][2 * rp + 1] * inv[2 * rp + 1];
                asm("v_cvt_pk_bf16_f32 %0, %1, %2" : "=v"(P2[hh][rp]) : "v"(lo), "v"(hi));
            }
        // ---- PV: own 4 heads, 16x16x16, o in AGPR ----
        const char* vb = smem + 32768 + cur * 16384 + vboff;
        #pragma unroll
        for (int hh = 0; hh < 4; ++hh) {
            i32x2 pa = (i32x2){(int)P2[hh][0], (int)P2[hh][1]};
            #pragma unroll
            for (int dt = 0; dt < 4; ++dt) {
                i32x2 vv = *(const i32x2*)(vb + hh * 2048 + dt * 512);
                asm("v_mfma_f32_16x16x16_bf16 %0, %1, %2, %0"
                    : "+a"(o[hh][dt]) : "v"(pa), "v"(vv));
            }
        }
        cur ^= 1;
    }
    // ---- store partial O (bf16): i = i0+wi*16+4g+r, d = (hg*4+hh)*64 + dt*16 + li ----
    {
        int irow0 = i0 + wi * 16 + 4 * g;
        #pragma unroll
        for (int hh = 0; hh < 4; ++hh) {
            int d0 = (hg * 4 + hh) * 64;
            #pragma unroll
            for (int dt = 0; dt < 4; ++dt) {
                #pragma unroll
                for (int r = 0; r < 4; ++r) {
                    int irow = irow0 + r;
                    if (irow <= 2048) {
                        Op[(((size_t)(nc * 2 + b)) * 2049 + irow) * 512 + d0 + dt * 16 + li] =
                            bf16rnd(o[hh][dt][r]);
                    }
                }
            }
        }
    }
}

// ---------------- sum NCJ bf16 partials -> bf16 attno ----------------
__global__ __launch_bounds__(256) void osum_kernel(
    const ushort* __restrict__ Op, ushort* __restrict__ attno)
{
    int idx = blockIdx.x * 256 + threadIdx.x;
    if (idx >= MROWS * 64) return;
    int row = idx >> 6, dq = idx & 63;
    int b = row / NTOK, i = row - b * NTOK;
    float acc[8];
    #pragma unroll
    for (int e = 0; e < 8; ++e) acc[e] = 0.f;
    #pragma unroll
    for (int nc = 0; nc < NCJ; ++nc) {
        const ushort* src = Op + (((size_t)(nc * 2 + b)) * 2049 + i) * 512 + dq * 8;
        int4 v = *(const int4*)src;
        const ushort* up = (const ushort*)&v;
        #pragma unroll
        for (int e = 0; e < 8; ++e) acc[e] += bf16tof(up[e]);
    }
    ushort ov[8];
    #pragma unroll
    for (int e = 0; e < 8; ++e) ov[e] = bf16rnd(acc[e]);
    *(int4*)(attno + (size_t)row * 512 + dq * 8) = *(int4*)ov;
}

// ---------------- head ----------------
__global__ void head_kernel(
    const float* __restrict__ x, const float* __restrict__ g, const float* __restrict__ b,
    const float* __restrict__ w, const float* __restrict__ hb, float* __restrict__ out)
{
    int lane = threadIdx.x & 63;
    for (int bi = 0; bi < 2; ++bi) {
        const float* xr = x + (size_t)bi * NTOK * 128;
        float v0 = xr[lane], v1 = xr[lane + 64];
        float mean = wave_allreduce_sum(v0 + v1) * (1.0f / 128.0f);
        float d0 = v0 - mean, d1 = v1 - mean;
        float var = wave_allreduce_sum(d0 * d0 + d1 * d1) * (1.0f / 128.0f);
        float inv = rsqrtf(var + 1e-5f);
        float y0 = d0 * inv * g[lane] + b[lane];
        float y1 = d1 * inv * g[lane + 64] + b[lane + 64];
        for (int c = 0; c < 4; ++c) {
            float pt = y0 * w[lane * 4 + c] + y1 * w[(lane + 64) * 4 + c];
            pt = wave_allreduce_sum(pt);
            if (lane == 0) out[bi * 4 + c] = pt + hb[c];
        }
    }
}

extern "C" void kernel_launch(void* const* d_in, const int* in_sizes, int n_in,
                              void* d_out, int out_size, void* d_ws, size_t ws_size,
                              hipStream_t stream) {
    const float* eeg   = (const float*)d_in[0];
    const float* est   = (const float*)d_in[1];
    const int*   cvi   = (const int*)d_in[2];
    const float* convw = (const float*)d_in[3];
    const float* convb = (const float*)d_in[4];
    const float* cls   = (const float*)d_in[5];
    const float* clsp  = (const float*)d_in[6];
    const float* bte   = (const float*)d_in[7];
    const float* btr   = (const float*)d_in[8];
    const float* bcr   = (const float*)d_in[9];
    const float* bce   = (const float*)d_in[10];
    const float* ln1g  = (const float*)d_in[11];
    const float* ln1b  = (const float*)d_in[12];
    const float* wqkv  = (const float*)d_in[13];
    const float* wkt   = (const float*)d_in[14];
    const float* wkc   = (const float*)d_in[15];
    const float* wo    = (const float*)d_in[16];
    const float* bo    = (const float*)d_in[17];
    const float* ln2g  = (const float*)d_in[18];
    const float* ln2b  = (const float*)d_in[19];
    const float* w1    = (const float*)d_in[20];
    const float* b1    = (const float*)d_in[21];
    const float* w2    = (const float*)d_in[22];
    const float* b2    = (const float*)d_in[23];
    const float* hlng  = (const float*)d_in[24];
    const float* hlnb  = (const float*)d_in[25];
    const float* hw    = (const float*)d_in[26];
    const float* hb    = (const float*)d_in[27];

    float* ws    = (float*)d_ws;
    float* x_    = ws + OFF_X;
    ushort* xnb  = (ushort*)(ws + OFF_XNB);
    ushort* rtb  = (ushort*)(ws + OFF_RTB);
    ushort* rcb  = (ushort*)(ws + OFF_RCB);
    ushort* qkvb = (ushort*)(ws + OFF_QKVB);
    ushort* ktcb = (ushort*)(ws + OFF_KTCB);
    ushort* ksb  = (ushort*)(ws + OFF_KSB);
    ushort* vtb  = (ushort*)(ws + OFF_VTB);
    float* colb_ = ws + OFF_COLB;
    ushort* wT   = (ushort*)(ws + OFF_WT);
    ushort* opb  = (ushort*)(ws + OFF_OP);
    ushort* attnob = (ushort*)(ws + OFF_ATTNO);
    ushort* ffnhb  = (ushort*)(ws + OFF_FFNH);

    wprep_kernel<<<dim3(768, 5, 2), 256, 0, stream>>>(wqkv, wkt, wkc, wo, w1, w2, wT);
    embed_kernel<<<4098, 128, 0, stream>>>(eeg, est, cvi, convw, convb, cls, clsp, x_, rtb, rcb);

    for (int l = 0; l < 2; ++l) {
        const ushort* wTl = wT + (size_t)l * 524288;
        ln_kernel<<<1025, 256, 0, stream>>>(x_, ln1g + l * 128, ln1b + l * 128, xnb, MROWS);
        mgemm_kernel<<<dim3(12, 33), 256, 0, stream>>>(xnb, xnb, 128, wTl,
                                                       nullptr, qkvb, nullptr, nullptr,
                                                       MROWS, 128, 1536, 3);
        mgemm_kernel<<<dim3(4, 33), 256, 0, stream>>>(rtb, rcb, 128, wTl + 196608,
                                                      nullptr, ktcb, nullptr, nullptr,
                                                      MROWS, 256, 512, 3);
        remap_kernel<<<MROWS + 30, 512, 0, stream>>>(qkvb, ktcb, bte, btr, bcr, bce,
                                                     ksb, colb_);
        vtrans_kernel<<<dim3(65, 16, 2), 256, 0, stream>>>(qkvb, vtb);
        attn9_kernel<<<dim3(65, NCJ, 2), 256, 0, stream>>>(qkvb, ksb, vtb, colb_, opb);
        osum_kernel<<<1025, 256, 0, stream>>>(opb, attnob);
        tgemm_kernel<<<dim3(8, 65), 256, 0, stream>>>(attnob, wTl + 327680, x_,
                                                      bo + l * 128, x_, MROWS, 128);
        ln_kernel<<<1025, 256, 0, stream>>>(x_, ln2g + l * 128, ln2b + l * 128, xnb, MROWS);
        mgemm_kernel<<<dim3(4, 33), 256, 0, stream>>>(xnb, xnb, 128, wTl + 393216,
                                                      nullptr, ffnhb, b1 + l * 512, nullptr,
                                                      MROWS, 128, 512, 2);
        tgemm_kernel<<<dim3(8, 65), 256, 0, stream>>>(ffnhb, wTl + 458752, x_,
                                                      b2 + l * 128, x_, MROWS, 128);
    }
    head_kernel<<<1, 64, 0, stream>>>(x_, hlng, hlnb, hw, hb, (float*)d_out);
}

// Round 17
// 320.406 us; speedup vs baseline: 1.0757x; 1.0757x over previous
//
#include <hip/hip_runtime.h>

#define CH    64
#define NTOK  2049
#define NTOKP 2064
#define MROWS 4098
#define NCJ   3

typedef __attribute__((ext_vector_type(8))) short bf16x8;
typedef __attribute__((ext_vector_type(4))) float f32x4;
typedef __attribute__((ext_vector_type(2))) int i32x2;

// workspace offsets (float units)
#define OFF_X     0u
#define OFF_XNB   524544u
#define OFF_RTB   786816u
#define OFF_RCB   1049088u
#define OFF_QKVB  1311360u
#define OFF_KTCB  4458624u
#define OFF_KSB   6556800u
#define OFF_VTB   8662656u
#define OFF_COLB  9727616u
#define OFF_WT    9760640u
#define OFF_OP    10284928u
#define OFF_ATTNO 13432192u
#define OFF_FFNH  14481280u

// 0.125 * log2(e): folds SCALE and exp->exp2 conversion into ksum/colb pre-scale
#define QSCALE 0.1803368801111204f

#define GLOAD_LDS16(gp, lp) __builtin_amdgcn_global_load_lds( \
    (const __attribute__((address_space(1))) void*)(gp), \
    (__attribute__((address_space(3))) void*)(lp), 16, 0, 0)

__device__ __forceinline__ float wave_allreduce_sum(float v) {
    #pragma unroll
    for (int m = 1; m < 64; m <<= 1) v += __shfl_xor(v, m);
    return v;
}

__device__ __forceinline__ ushort bf16rnd(float x) {
    unsigned u = __builtin_bit_cast(unsigned, x);
    u += 0x7FFF + ((u >> 16) & 1);
    return (ushort)(u >> 16);
}

__device__ __forceinline__ float bf16tof(ushort u) {
    return __builtin_bit_cast(float, ((unsigned)u) << 16);
}

// ---------------- weight prep: f32 [K][N] -> bf16 Wt [N][K] (ktc concatenated) ----------------
__global__ __launch_bounds__(256) void wprep_kernel(
    const float* __restrict__ wqkv, const float* __restrict__ wkt, const float* __restrict__ wkc,
    const float* __restrict__ wo, const float* __restrict__ w1, const float* __restrict__ w2,
    ushort* __restrict__ wT)
{
    int l = blockIdx.z, mat = blockIdx.y;
    int idx = blockIdx.x * 256 + threadIdx.x;
    float v; int off;
    if (mat == 0) {            // qkv: N=1536 K=128
        if (idx >= 196608) return;
        int n = idx >> 7, k = idx & 127;
        v = wqkv[(size_t)l * 196608 + (size_t)k * 1536 + n]; off = 0;
    } else if (mat == 1) {     // ktc: N=512 K=256 (wkt | wkc)
        if (idx >= 131072) return;
        int n = idx >> 8, k = idx & 255;
        v = (k < 128) ? wkt[(size_t)l * 65536 + (size_t)k * 512 + n]
                      : wkc[(size_t)l * 65536 + (size_t)(k - 128) * 512 + n];
        off = 196608;
    } else if (mat == 2) {     // wo: N=128 K=512
        if (idx >= 65536) return;
        int n = idx >> 9, k = idx & 511;
        v = wo[(size_t)l * 65536 + (size_t)k * 128 + n]; off = 327680;
    } else if (mat == 3) {     // w1: N=512 K=128
        if (idx >= 65536) return;
        int n = idx >> 7, k = idx & 127;
        v = w1[(size_t)l * 65536 + (size_t)k * 512 + n]; off = 393216;
    } else {                   // w2: N=128 K=512
        if (idx >= 65536) return;
        int n = idx >> 9, k = idx & 511;
        v = w2[(size_t)l * 65536 + (size_t)k * 128 + n]; off = 458752;
    }
    wT[(size_t)l * 524288 + off + idx] = bf16rnd(v);
}

// ---------------- embed ----------------
__global__ __launch_bounds__(128) void embed_kernel(
    const float* __restrict__ eeg, const float* __restrict__ est, const int* __restrict__ cvi,
    const float* __restrict__ cw, const float* __restrict__ cb,
    const float* __restrict__ cls, const float* __restrict__ clsp,
    float* __restrict__ x, ushort* __restrict__ rt, ushort* __restrict__ rc)
{
    int id = blockIdx.x;
    int d = threadIdx.x;
    if (id >= 4096) {
        int b = id - 4096;
        size_t base = (size_t)b * NTOK * 128 + d;
        x[base]  = cls[d];
        rt[base] = bf16rnd(clsp[d]);
        rc[base] = bf16rnd(clsp[d]);
        return;
    }
    int b = id >> 11, rem = id & 2047, c = rem >> 5, w = rem & 31;
    __shared__ float xs[25];
    if (d < 25) xs[d] = eeg[((size_t)(b * CH + c)) * 800 + w * 25 + d];
    __syncthreads();
    float acc = cb[d];
    #pragma unroll
    for (int p = 0; p < 25; ++p) acc += xs[p] * cw[d * 25 + p];
    int i = 1 + c * 32 + w;
    size_t base = ((size_t)b * NTOK + i) * 128 + d;
    x[base] = acc;
    int k = d & 63;
    float invk = __expf(-0.14391156831f * (float)k);
    float pt = floorf(est[b] / 0.1f) + (float)w;
    float at = pt * invk;
    rt[base] = bf16rnd((d < 64) ? sinf(at) : cosf(at));
    float pc = (float)cvi[b * CH + c];
    float ac = pc * invk;
    rc[base] = bf16rnd((d < 64) ? sinf(ac) : cosf(ac));
}

// ---------------- layernorm, bf16 out ----------------
__global__ __launch_bounds__(256) void ln_kernel(
    const float* __restrict__ x, const float* __restrict__ g, const float* __restrict__ bb,
    ushort* __restrict__ out, int rows)
{
    int w = threadIdx.x >> 6, lane = threadIdx.x & 63;
    int row = blockIdx.x * 4 + w;
    if (row >= rows) return;
    const float* xr = x + (size_t)row * 128;
    float v0 = xr[lane], v1 = xr[lane + 64];
    float mean = wave_allreduce_sum(v0 + v1) * (1.0f / 128.0f);
    float d0 = v0 - mean, d1 = v1 - mean;
    float var = wave_allreduce_sum(d0 * d0 + d1 * d1) * (1.0f / 128.0f);
    float inv = rsqrtf(var + 1e-5f);
    out[(size_t)row * 128 + lane]      = bf16rnd(d0 * inv * g[lane]      + bb[lane]);
    out[(size_t)row * 128 + lane + 64] = bf16rnd(d1 * inv * g[lane + 64] + bb[lane + 64]);
}

// ---------------- fused qkv+ktc bf16 MFMA GEMM (one dispatch, 528 blocks) ----------------
// blockIdx.x < 12: C=qkvb = xnb[Mx128] @ wT_qkv[1536x128]^T      (N=1536, K=128)
// blockIdx.x >=12: C=ktcb = (rtb|rcb)[Mx256] @ wT_ktc[512x256]^T (N=512,  K=256)
__global__ __launch_bounds__(256, 3) void mgemm2_kernel(
    const ushort* __restrict__ xnb, const ushort* __restrict__ rtb, const ushort* __restrict__ rcb,
    const ushort* __restrict__ wTl, ushort* __restrict__ qkvb, ushort* __restrict__ ktcb, int M)
{
    __shared__ ushort Alds[128 * 72];
    __shared__ ushort Blds[128 * 72];
    const bool isq = (blockIdx.x < 12);
    const ushort* A  = isq ? xnb : rtb;
    const ushort* A2 = isq ? xnb : rcb;
    const ushort* Wt = isq ? wTl : (wTl + 196608);
    ushort* outB = isq ? qkvb : ktcb;
    const int K1 = 128;
    const int K  = isq ? 128 : 256;
    const int N  = isq ? 1536 : 512;
    const int n0 = (isq ? blockIdx.x : (blockIdx.x - 12)) * 128;
    const int K2s = K - K1;

    int tid = threadIdx.x;
    int lane = tid & 63, wv = tid >> 6;
    int wm = wv >> 1, wn = wv & 1;
    int li = lane & 15, g = lane >> 4;
    int m0 = blockIdx.y * 128;
    f32x4 acc[4][4];
    #pragma unroll
    for (int a = 0; a < 4; ++a)
        #pragma unroll
        for (int c = 0; c < 4; ++c) acc[a][c] = (f32x4){0.f, 0.f, 0.f, 0.f};

    for (int kb = 0; kb < K; kb += 64) {
        #pragma unroll
        for (int it = 0; it < 4; ++it) {
            int gi = tid + it * 256;
            int row = gi >> 3, gc = gi & 7;
            int m = m0 + row; if (m >= M) m = M - 1;
            int acol = kb + gc * 8;
            const ushort* asrc = (acol < K1) ? (A + (size_t)m * K1 + acol)
                                             : (A2 + (size_t)m * K2s + (acol - K1));
            bf16x8 av = *(const bf16x8*)asrc;
            *(bf16x8*)&Alds[row * 72 + ((gc ^ (row & 7)) << 3)] = av;
            int n = n0 + row;
            bf16x8 bv = *(const bf16x8*)(Wt + (size_t)n * K + acol);
            *(bf16x8*)&Blds[row * 72 + ((gc ^ (row & 7)) << 3)] = bv;
        }
        __syncthreads();
        #pragma unroll
        for (int k2 = 0; k2 < 2; ++k2) {
            bf16x8 af[4], bfr[4];
            #pragma unroll
            for (int xx = 0; xx < 4; ++xx) {
                int ra = wm * 64 + xx * 16 + li;
                int rb = wn * 64 + xx * 16 + li;
                af[xx]  = *(const bf16x8*)&Alds[ra * 72 + (((k2 * 4 + g) ^ (ra & 7)) << 3)];
                bfr[xx] = *(const bf16x8*)&Blds[rb * 72 + (((k2 * 4 + g) ^ (rb & 7)) << 3)];
            }
            #pragma unroll
            for (int mi = 0; mi < 4; ++mi)
                #pragma unroll
                for (int ni = 0; ni < 4; ++ni)
                    acc[mi][ni] = __builtin_amdgcn_mfma_f32_16x16x32_bf16(af[mi], bfr[ni], acc[mi][ni], 0, 0, 0);
        }
        __syncthreads();
    }
    #pragma unroll
    for (int mi = 0; mi < 4; ++mi) {
        #pragma unroll
        for (int r = 0; r < 4; ++r) {
            int m = m0 + wm * 64 + mi * 16 + 4 * g + r;
            if (m >= M) continue;
            #pragma unroll
            for (int ni = 0; ni < 4; ++ni) {
                int n = n0 + wn * 64 + ni * 16 + li;
                outB[(size_t)m * N + n] = bf16rnd(acc[mi][ni][r]);
            }
        }
    }
}

// ---------------- bf16 MFMA GEMM (ffn w1, gelu): C = A[MxK] * Wt[NxK] ----------------
__global__ __launch_bounds__(256, 3) void mgemm_kernel(
    const ushort* __restrict__ A, const ushort* __restrict__ Wt,
    ushort* outB, const float* bias, int M, int K, int N)
{
    __shared__ ushort Alds[128 * 72];
    __shared__ ushort Blds[128 * 72];
    int tid = threadIdx.x;
    int lane = tid & 63, wv = tid >> 6;
    int wm = wv >> 1, wn = wv & 1;
    int li = lane & 15, g = lane >> 4;
    int m0 = blockIdx.y * 128, n0 = blockIdx.x * 128;
    f32x4 acc[4][4];
    #pragma unroll
    for (int a = 0; a < 4; ++a)
        #pragma unroll
        for (int c = 0; c < 4; ++c) acc[a][c] = (f32x4){0.f, 0.f, 0.f, 0.f};

    for (int kb = 0; kb < K; kb += 64) {
        #pragma unroll
        for (int it = 0; it < 4; ++it) {
            int gi = tid + it * 256;
            int row = gi >> 3, gc = gi & 7;
            int m = m0 + row; if (m >= M) m = M - 1;
            int acol = kb + gc * 8;
            bf16x8 av = *(const bf16x8*)(A + (size_t)m * K + acol);
            *(bf16x8*)&Alds[row * 72 + ((gc ^ (row & 7)) << 3)] = av;
            int n = n0 + row;
            bf16x8 bv = *(const bf16x8*)(Wt + (size_t)n * K + acol);
            *(bf16x8*)&Blds[row * 72 + ((gc ^ (row & 7)) << 3)] = bv;
        }
        __syncthreads();
        #pragma unroll
        for (int k2 = 0; k2 < 2; ++k2) {
            bf16x8 af[4], bfr[4];
            #pragma unroll
            for (int xx = 0; xx < 4; ++xx) {
                int ra = wm * 64 + xx * 16 + li;
                int rb = wn * 64 + xx * 16 + li;
                af[xx]  = *(const bf16x8*)&Alds[ra * 72 + (((k2 * 4 + g) ^ (ra & 7)) << 3)];
                bfr[xx] = *(const bf16x8*)&Blds[rb * 72 + (((k2 * 4 + g) ^ (rb & 7)) << 3)];
            }
            #pragma unroll
            for (int mi = 0; mi < 4; ++mi)
                #pragma unroll
                for (int ni = 0; ni < 4; ++ni)
                    acc[mi][ni] = __builtin_amdgcn_mfma_f32_16x16x32_bf16(af[mi], bfr[ni], acc[mi][ni], 0, 0, 0);
        }
        __syncthreads();
    }
    #pragma unroll
    for (int mi = 0; mi < 4; ++mi) {
        #pragma unroll
        for (int r = 0; r < 4; ++r) {
            int m = m0 + wm * 64 + mi * 16 + 4 * g + r;
            if (m >= M) continue;
            #pragma unroll
            for (int ni = 0; ni < 4; ++ni) {
                int n = n0 + wn * 64 + ni * 16 + li;
                float v = acc[mi][ni][r] + bias[n];
                v = 0.5f * v * (1.0f + erff(v * 0.70710678118f));
                outB[(size_t)m * N + n] = bf16rnd(v);
            }
        }
    }
}

// ---------------- thin GEMM (N=128, K=512): one 16x16 tile per wave, no LDS ----------------
__global__ __launch_bounds__(256) void tgemm_kernel(
    const ushort* __restrict__ A, const ushort* __restrict__ Wt,
    float* __restrict__ outF, const float* __restrict__ bias, const float* __restrict__ res,
    int M, int N)
{
    int lane = threadIdx.x & 63, wv = threadIdx.x >> 6;
    int li = lane & 15, g = lane >> 4;
    int mt = blockIdx.y * 4 + wv;
    int m0 = mt * 16, n0 = blockIdx.x * 16;
    int ar = m0 + li; if (ar >= M) ar = M - 1;
    const ushort* arow = A + (size_t)ar * 512 + 8 * g;
    const ushort* brow = Wt + (size_t)(n0 + li) * 512 + 8 * g;
    f32x4 acc = (f32x4){0.f, 0.f, 0.f, 0.f};
    #pragma unroll
    for (int k2 = 0; k2 < 16; ++k2) {
        bf16x8 af = *(const bf16x8*)(arow + k2 * 32);
        bf16x8 bf = *(const bf16x8*)(brow + k2 * 32);
        acc = __builtin_amdgcn_mfma_f32_16x16x32_bf16(af, bf, acc, 0, 0, 0);
    }
    #pragma unroll
    for (int r = 0; r < 4; ++r) {
        int m = m0 + 4 * g + r;
        if (m < M) {
            int n = n0 + li;
            outF[(size_t)m * N + n] = acc[r] + bias[n] + res[(size_t)m * N + n];
        }
    }
}

// ---------------- remap -> ksum(xQSCALE, padded) + colb(padded); zeroes pad rows ----------------
__global__ __launch_bounds__(512) void remap_kernel(
    const ushort* __restrict__ qkvb, const ushort* __restrict__ ktcb,
    const float* __restrict__ bte, const float* __restrict__ btr,
    const float* __restrict__ bcr, const float* __restrict__ bce,
    ushort* __restrict__ ksum, float* __restrict__ colb)
{
    int id = blockIdx.x;            // b2*NTOK + i2, or pad block
    int t = threadIdx.x;
    if (id >= MROWS) {              // zero pad rows j in [2049,2064) of ksum/colb
        int pidx = id - MROWS;
        int b2 = pidx / 15, i2 = 2049 + pidx % 15;
        ksum[((size_t)(b2 * NTOKP + i2)) * 512 + t] = 0;
        if (t < 8) colb[((size_t)(b2 * NTOKP + i2)) * 8 + t] = 0.0f;
        return;
    }
    int b2 = id / NTOK, i2 = id - b2 * NTOK;
    int h2 = t >> 6, d2 = t & 63;
    int G = i2 * 16 + b2 * 8 + h2;
    int bhA = G / 2049, iA = G - bhA * 2049;
    int bA = bhA >> 3, hA = bhA & 7;
    size_t qbase = ((size_t)(bA * NTOK + iA)) * 1536 + hA * 64 + d2;
    ushort kvu = qkvb[qbase + 512];
    int bB = G / 16392, remB = G - bB * 16392;
    int iB = remB >> 3, hB = remB & 7;
    ushort ktcu = ktcb[((size_t)(bB * NTOK + iB)) * 512 + hB * 64 + d2];
    float kv = bf16tof(kvu), ktcv = bf16tof(ktcu);
    ksum[((size_t)(b2 * NTOKP + i2)) * 512 + t] = bf16rnd((kv + ktcv) * QSCALE);
    float cbx = (bte[t] + bce[t]) * kv + (btr[t] + bcr[t]) * ktcv;
    cbx = wave_allreduce_sum(cbx);
    if (d2 == 0) colb[((size_t)(b2 * NTOKP + i2)) * 8 + h2] = cbx;
}

// ---------------- transpose V: qkvb (old space, inverse map) -> vt[b][d][j 2080] ----------------
__global__ __launch_bounds__(256) void vtrans_kernel(
    const ushort* __restrict__ qkvb, ushort* __restrict__ vt)
{
    __shared__ ushort tile[32][36];
    int jt = blockIdx.x, dt = blockIdx.y, b = blockIdx.z;
    int t = threadIdx.x;
    {
        int jj = t >> 3, dq = t & 7;
        int j = jt * 32 + jj;
        ushort4 v = make_ushort4(0, 0, 0, 0);
        if (j <= 2048) {
            int h2 = dt >> 1;
            int d2 = (dt & 1) * 32 + dq * 4;
            int G = j * 16 + b * 8 + h2;
            int bhA = G / 2049, iA = G - bhA * 2049;
            int bA = bhA >> 3, hA = bhA & 7;
            v = *(const ushort4*)(qkvb + ((size_t)(bA * NTOK + iA)) * 1536 + 1024 + hA * 64 + d2);
        }
        *(ushort4*)&tile[jj][dq * 4] = v;
    }
    __syncthreads();
    {
        int dd = t >> 3, jq = t & 7;
        ushort4 w;
        w.x = tile[jq * 4 + 0][dd];
        w.y = tile[jq * 4 + 1][dd];
        w.z = tile[jq * 4 + 2][dd];
        w.w = tile[jq * 4 + 3][dd];
        *(ushort4*)(vt + ((size_t)b * 512 + dt * 32 + dd) * 2080 + jt * 32 + jq * 4) = w;
    }
}

// ---------------- attn9: swapped-QK, heads split across wave pair + LDS sum-exchange ----------------
// Best-measured structure (85 us/layer). grid (65, NCJ=3, 2) = 390 blocks, 2 blocks/CU.
// Everything double-buffered; K/V/cb staged post-B2 (one full iteration of prefetch distance).
// LDS: K dbuf 2x16K @0 | V dbuf 2x16K @32768 | cb dbuf 2x768 @65536 | ex 4K @67072 = 69.4KB.
__global__ __launch_bounds__(256, 2) void attn9_kernel(
    const ushort* __restrict__ qkvb, const ushort* __restrict__ ks,
    const ushort* __restrict__ vt, const float* __restrict__ colb,
    ushort* __restrict__ Op)
{
    __shared__ __align__(16) char smem[71168];
    const int tid = threadIdx.x;
    const int lane = tid & 63, wv = tid >> 6;
    const int wi = wv >> 1, hg = wv & 1;
    const int g = lane >> 4, li = lane & 15;
    const int nc = blockIdx.y, b = blockIdx.z;
    const int i0 = blockIdx.x * 32;
    const int jt0 = nc * 43, jt1 = (nc + 1) * 43;

    // Q fragments: own 4 heads x 2 k2, gathered from qkvb (old space) via inverse map
    bf16x8 qf[4][2];
    {
        int iq = i0 + wi * 16 + li; if (iq > 2048) iq = 2048;
        #pragma unroll
        for (int hh = 0; hh < 4; ++hh) {
            int h2 = hg * 4 + hh;
            int G = iq * 16 + b * 8 + h2;
            int bhA = G / 2049, iA = G - bhA * 2049;
            int bA = bhA >> 3, hA = bhA & 7;
            const ushort* qrow = qkvb + ((size_t)(bA * NTOK + iA)) * 1536 + hA * 64 + 8 * g;
            qf[hh][0] = *(const bf16x8*)(qrow);
            qf[hh][1] = *(const bf16x8*)(qrow + 32);
        }
    }
    f32x4 o[4][4];   // own 4 heads x 4 d-subtiles -> AGPR
    #pragma unroll
    for (int a = 0; a < 4; ++a)
        #pragma unroll
        for (int m = 0; m < 4; ++m) o[a][m] = (f32x4){0.f, 0.f, 0.f, 0.f};

    // hoisted per-lane LDS read bases
    const unsigned koff0 = (unsigned)(li * 1024) + (unsigned)((g * 16) ^ ((li & 7) << 4))
                         + (unsigned)(hg * 512);
    const unsigned koff1 = (unsigned)(li * 1024) + (unsigned)((64 + g * 16) ^ ((li & 7) << 4))
                         + (unsigned)(hg * 512);
    const unsigned vboff = (unsigned)(li * 32)
                         + (unsigned)((((g >> 1) ^ ((li >> 2) & 1)) << 4) + (g & 1) * 8)
                         + (unsigned)(hg * 8192);
    const unsigned exoff = 67072u + (unsigned)(wv * 1024 + lane * 16);
    const unsigned exoffp = 67072u + (unsigned)((wv ^ 1) * 1024 + lane * 16);

    // staging (padded buffers: NO clamps, affine in jt)
    const ushort* ksb_b = ks + ((size_t)b * NTOKP) * 512;
    auto stageK = [&](int jt, int buf) {
        #pragma unroll
        for (int t = 0; t < 4; ++t) {
            unsigned L = (unsigned)((wv * 256 + t * 64 + lane) * 16);
            unsigned Lp = L ^ (((L >> 10) & 7u) << 4);
            const ushort* src = ksb_b + (size_t)(jt * 16 + (int)(Lp >> 10)) * 512 + ((Lp & 1023u) >> 1);
            GLOAD_LDS16(src, smem + buf * 16384 + (wv * 256 + t * 64) * 16);
        }
    };
    const ushort* vtb_b = vt + (size_t)b * 512 * 2080;
    auto stageV = [&](int jt, int buf) {
        #pragma unroll
        for (int t = 0; t < 4; ++t) {
            int n = wv * 256 + t * 64 + lane;
            int d = n >> 1;
            int h16 = (n & 1) ^ ((n >> 3) & 1);
            const ushort* src = vtb_b + (size_t)d * 2080 + jt * 16 + h16 * 8;
            GLOAD_LDS16(src, smem + 32768 + buf * 16384 + (wv * 256 + t * 64) * 16);
        }
    };
    auto loadcb = [&](int jt) -> float {
        if (tid < 128) {
            int jg = jt * 16 + (tid >> 3);
            if (jg > 2063) jg = 2063;      // pad rows are zero; just keep in-bounds
            return colb[((size_t)(b * NTOKP + jg)) * 8 + (tid & 7)] * QSCALE;
        }
        return 0.f;
    };

    stageK(jt0, 0); stageV(jt0, 0);
    {
        float c0 = loadcb(jt0);
        if (tid < 128) ((float*)(smem + 65536))[(tid >> 3) * 12 + (tid & 7)] = c0;
    }
    float cbreg = loadcb(jt0 + 1);

    int cur = 0;
    for (int jt = jt0; jt < jt1; ++jt) {
        __syncthreads();   // B1: staging(jt)+cb(jt) visible; prev ex reads done
        // ---- QK (swapped): s[hh](j=4g+r, i=li), own 4 heads only ----
        const char* kb = smem + cur * 16384;
        f32x4 s[4];
        #pragma unroll
        for (int hh = 0; hh < 4; ++hh) {
            s[hh] = (f32x4){0.f, 0.f, 0.f, 0.f};
            bf16x8 kf0 = *(const bf16x8*)(kb + koff0 + hh * 128);
            s[hh] = __builtin_amdgcn_mfma_f32_16x16x32_bf16(kf0, qf[hh][0], s[hh], 0, 0, 0);
            bf16x8 kf1 = *(const bf16x8*)(kb + koff1 + hh * 128);
            s[hh] = __builtin_amdgcn_mfma_f32_16x16x32_bf16(kf1, qf[hh][1], s[hh], 0, 0, 0);
        }
        // ---- exp2 own heads + partial head-sum -> LDS exchange ----
        const float* cbl = (const float*)(smem + 65536 + cur * 768);
        float p[4][4];
        #pragma unroll
        for (int rp = 0; rp < 2; ++rp) {
            f32x4 ce = *(const f32x4*)(cbl + (4 * g + 2 * rp) * 12 + hg * 4);
            f32x4 co = *(const f32x4*)(cbl + (4 * g + 2 * rp) * 12 + 12 + hg * 4);
            #pragma unroll
            for (int hh = 0; hh < 4; ++hh) {
                p[hh][2 * rp]     = __builtin_amdgcn_exp2f(s[hh][2 * rp]     + ce[hh]);
                p[hh][2 * rp + 1] = __builtin_amdgcn_exp2f(s[hh][2 * rp + 1] + co[hh]);
            }
        }
        f32x4 e;
        #pragma unroll
        for (int r = 0; r < 4; ++r)
            e[r] = (p[0][r] + p[1][r]) + (p[2][r] + p[3][r]);
        *(f32x4*)(smem + exoff) = e;
        __syncthreads();   // B2: exchange visible (staging(jt) long drained)
        f32x4 eo = *(const f32x4*)(smem + exoffp);
        // ---- issue next-tile staging + cb write NOW (post-B2: latency spans PV + next QK) ----
        const bool hn = (jt + 1 < jt1);
        if (hn) {
            if (tid < 128) ((float*)(smem + 65536 + (cur ^ 1) * 768))[(tid >> 3) * 12 + (tid & 7)] = cbreg;
            stageK(jt + 1, cur ^ 1);
            stageV(jt + 1, cur ^ 1);
            cbreg = loadcb(jt + 2);
        }
        // ---- full softmax denominator, pack P (PV A-operand) ----
        float inv[4];
        #pragma unroll
        for (int r = 0; r < 4; ++r)
            inv[r] = __builtin_amdgcn_rcpf(fmaxf(e[r] + eo[r], 1e-20f));  // NORMAL floor
        unsigned P2[4][2];
        #pragma unroll
        for (int hh = 0; hh < 4; ++hh)
            #pragma unroll
            for (int rp = 0; rp < 2; ++rp) {
                float lo = p[hh][2 * rp] * inv[2 * rp];
                float hi = p[hh][2 * rp + 1] * inv[2 * rp + 1];
                asm("v_cvt_pk_bf16_f32 %0, %1, %2" : "=v"(P2[hh][rp]) : "v"(lo), "v"(hi));
            }
        // ---- PV: own 4 heads, 16x16x16, o in AGPR ----
        const char* vb = smem + 32768 + cur * 16384 + vboff;
        #pragma unroll
        for (int hh = 0; hh < 4; ++hh) {
            i32x2 pa = (i32x2){(int)P2[hh][0], (int)P2[hh][1]};
            #pragma unroll
            for (int dt = 0; dt < 4; ++dt) {
                i32x2 vv = *(const i32x2*)(vb + hh * 2048 + dt * 512);
                asm("v_mfma_f32_16x16x16_bf16 %0, %1, %2, %0"
                    : "+a"(o[hh][dt]) : "v"(pa), "v"(vv));
            }
        }
        cur ^= 1;
    }
    // ---- store partial O (bf16): i = i0+wi*16+4g+r, d = (hg*4+hh)*64 + dt*16 + li ----
    {
        int irow0 = i0 + wi * 16 + 4 * g;
        #pragma unroll
        for (int hh = 0; hh < 4; ++hh) {
            int d0 = (hg * 4 + hh) * 64;
            #pragma unroll
            for (int dt = 0; dt < 4; ++dt) {
                #pragma unroll
                for (int r = 0; r < 4; ++r) {
                    int irow = irow0 + r;
                    if (irow <= 2048) {
                        Op[(((size_t)(nc * 2 + b)) * 2049 + irow) * 512 + d0 + dt * 16 + li] =
                            bf16rnd(o[hh][dt][r]);
                    }
                }
            }
        }
    }
}

// ---------------- sum NCJ bf16 partials -> bf16 attno ----------------
__global__ __launch_bounds__(256) void osum_kernel(
    const ushort* __restrict__ Op, ushort* __restrict__ attno)
{
    int idx = blockIdx.x * 256 + threadIdx.x;
    if (idx >= MROWS * 64) return;
    int row = idx >> 6, dq = idx & 63;
    int b = row / NTOK, i = row - b * NTOK;
    float acc[8];
    #pragma unroll
    for (int e = 0; e < 8; ++e) acc[e] = 0.f;
    #pragma unroll
    for (int nc = 0; nc < NCJ; ++nc) {
        const ushort* src = Op + (((size_t)(nc * 2 + b)) * 2049 + i) * 512 + dq * 8;
        int4 v = *(const int4*)src;
        const ushort* up = (const ushort*)&v;
        #pragma unroll
        for (int e = 0; e < 8; ++e) acc[e] += bf16tof(up[e]);
    }
    ushort ov[8];
    #pragma unroll
    for (int e = 0; e < 8; ++e) ov[e] = bf16rnd(acc[e]);
    *(int4*)(attno + (size_t)row * 512 + dq * 8) = *(int4*)ov;
}

// ---------------- head ----------------
__global__ void head_kernel(
    const float* __restrict__ x, const float* __restrict__ g, const float* __restrict__ b,
    const float* __restrict__ w, const float* __restrict__ hb, float* __restrict__ out)
{
    int lane = threadIdx.x & 63;
    for (int bi = 0; bi < 2; ++bi) {
        const float* xr = x + (size_t)bi * NTOK * 128;
        float v0 = xr[lane], v1 = xr[lane + 64];
        float mean = wave_allreduce_sum(v0 + v1) * (1.0f / 128.0f);
        float d0 = v0 - mean, d1 = v1 - mean;
        float var = wave_allreduce_sum(d0 * d0 + d1 * d1) * (1.0f / 128.0f);
        float inv = rsqrtf(var + 1e-5f);
        float y0 = d0 * inv * g[lane] + b[lane];
        float y1 = d1 * inv * g[lane + 64] + b[lane + 64];
        for (int c = 0; c < 4; ++c) {
            float pt = y0 * w[lane * 4 + c] + y1 * w[(lane + 64) * 4 + c];
            pt = wave_allreduce_sum(pt);
            if (lane == 0) out[bi * 4 + c] = pt + hb[c];
        }
    }
}

extern "C" void kernel_launch(void* const* d_in, const int* in_sizes, int n_in,
                              void* d_out, int out_size, void* d_ws, size_t ws_size,
                              hipStream_t stream) {
    const float* eeg   = (const float*)d_in[0];
    const float* est   = (const float*)d_in[1];
    const int*   cvi   = (const int*)d_in[2];
    const float* convw = (const float*)d_in[3];
    const float* convb = (const float*)d_in[4];
    const float* cls   = (const float*)d_in[5];
    const float* clsp  = (const float*)d_in[6];
    const float* bte   = (const float*)d_in[7];
    const float* btr   = (const float*)d_in[8];
    const float* bcr   = (const float*)d_in[9];
    const float* bce   = (const float*)d_in[10];
    const float* ln1g  = (const float*)d_in[11];
    const float* ln1b  = (const float*)d_in[12];
    const float* wqkv  = (const float*)d_in[13];
    const float* wkt   = (const float*)d_in[14];
    const float* wkc   = (const float*)d_in[15];
    const float* wo    = (const float*)d_in[16];
    const float* bo    = (const float*)d_in[17];
    const float* ln2g  = (const float*)d_in[18];
    const float* ln2b  = (const float*)d_in[19];
    const float* w1    = (const float*)d_in[20];
    const float* b1    = (const float*)d_in[21];
    const float* w2    = (const float*)d_in[22];
    const float* b2    = (const float*)d_in[23];
    const float* hlng  = (const float*)d_in[24];
    const float* hlnb  = (const float*)d_in[25];
    const float* hw    = (const float*)d_in[26];
    const float* hb    = (const float*)d_in[27];

    float* ws    = (float*)d_ws;
    float* x_    = ws + OFF_X;
    ushort* xnb  = (ushort*)(ws + OFF_XNB);
    ushort* rtb  = (ushort*)(ws + OFF_RTB);
    ushort* rcb  = (ushort*)(ws + OFF_RCB);
    ushort* qkvb = (ushort*)(ws + OFF_QKVB);
    ushort* ktcb = (ushort*)(ws + OFF_KTCB);
    ushort* ksb  = (ushort*)(ws + OFF_KSB);
    ushort* vtb  = (ushort*)(ws + OFF_VTB);
    float* colb_ = ws + OFF_COLB;
    ushort* wT   = (ushort*)(ws + OFF_WT);
    ushort* opb  = (ushort*)(ws + OFF_OP);
    ushort* attnob = (ushort*)(ws + OFF_ATTNO);
    ushort* ffnhb  = (ushort*)(ws + OFF_FFNH);

    wprep_kernel<<<dim3(768, 5, 2), 256, 0, stream>>>(wqkv, wkt, wkc, wo, w1, w2, wT);
    embed_kernel<<<4098, 128, 0, stream>>>(eeg, est, cvi, convw, convb, cls, clsp, x_, rtb, rcb);

    for (int l = 0; l < 2; ++l) {
        const ushort* wTl = wT + (size_t)l * 524288;
        ln_kernel<<<1025, 256, 0, stream>>>(x_, ln1g + l * 128, ln1b + l * 128, xnb, MROWS);
        mgemm2_kernel<<<dim3(16, 33), 256, 0, stream>>>(xnb, rtb, rcb, wTl, qkvb, ktcb, MROWS);
        remap_kernel<<<MROWS + 30, 512, 0, stream>>>(qkvb, ktcb, bte, btr, bcr, bce,
                                                     ksb, colb_);
        vtrans_kernel<<<dim3(65, 16, 2), 256, 0, stream>>>(qkvb, vtb);
        attn9_kernel<<<dim3(65, NCJ, 2), 256, 0, stream>>>(qkvb, ksb, vtb, colb_, opb);
        osum_kernel<<<1025, 256, 0, stream>>>(opb, attnob);
        tgemm_kernel<<<dim3(8, 65), 256, 0, stream>>>(attnob, wTl + 327680, x_,
                                                      bo + l * 128, x_, MROWS, 128);
        ln_kernel<<<1025, 256, 0, stream>>>(x_, ln2g + l * 128, ln2b + l * 128, xnb, MROWS);
        mgemm_kernel<<<dim3(4, 33), 256, 0, stream>>>(xnb, wTl + 393216, ffnhb,
                                                      b1 + l * 512, MROWS, 128, 512);
        tgemm_kernel<<<dim3(8, 65), 256, 0, stream>>>(ffnhb, wTl + 458752, x_,
                                                      b2 + l * 128, x_, MROWS, 128);
    }
    head_kernel<<<1, 64, 0, stream>>>(x_, hlng, hlnb, hw, hb, (float*)d_out);
}

// Round 18
// 313.101 us; speedup vs baseline: 1.1008x; 1.0233x over previous
//
#include <hip/hip_runtime.h>

#define CH    64
#define NTOK  2049
#define NTOKP 2064
#define MROWS 4098
#define NCJ   3

typedef __attribute__((ext_vector_type(8))) short bf16x8;
typedef __attribute__((ext_vector_type(4))) float f32x4;
typedef __attribute__((ext_vector_type(2))) int i32x2;

// workspace offsets (float units)
#define OFF_X     0u
#define OFF_XNB   524544u
#define OFF_RTB   786816u
#define OFF_RCB   1049088u
#define OFF_QKVB  1311360u
#define OFF_KTCB  4458624u
#define OFF_KSB   6556800u
#define OFF_VTB   8662656u
#define OFF_COLB  9727616u
#define OFF_WT    9760640u
#define OFF_OP    10284928u
#define OFF_ATTNO 13432192u
#define OFF_FFNH  14481280u

// 0.125 * log2(e): folds SCALE and exp->exp2 conversion into ksum/colb pre-scale
#define QSCALE 0.1803368801111204f

#define GLOAD_LDS16(gp, lp) __builtin_amdgcn_global_load_lds( \
    (const __attribute__((address_space(1))) void*)(gp), \
    (__attribute__((address_space(3))) void*)(lp), 16, 0, 0)

__device__ __forceinline__ float wave_allreduce_sum(float v) {
    #pragma unroll
    for (int m = 1; m < 64; m <<= 1) v += __shfl_xor(v, m);
    return v;
}

__device__ __forceinline__ ushort bf16rnd(float x) {
    unsigned u = __builtin_bit_cast(unsigned, x);
    u += 0x7FFF + ((u >> 16) & 1);
    return (ushort)(u >> 16);
}

__device__ __forceinline__ float bf16tof(ushort u) {
    return __builtin_bit_cast(float, ((unsigned)u) << 16);
}

// ---------------- weight prep: f32 [K][N] -> bf16 Wt [N][K] (ktc concatenated) ----------------
__global__ __launch_bounds__(256) void wprep_kernel(
    const float* __restrict__ wqkv, const float* __restrict__ wkt, const float* __restrict__ wkc,
    const float* __restrict__ wo, const float* __restrict__ w1, const float* __restrict__ w2,
    ushort* __restrict__ wT)
{
    int l = blockIdx.z, mat = blockIdx.y;
    int idx = blockIdx.x * 256 + threadIdx.x;
    float v; int off;
    if (mat == 0) {            // qkv: N=1536 K=128
        if (idx >= 196608) return;
        int n = idx >> 7, k = idx & 127;
        v = wqkv[(size_t)l * 196608 + (size_t)k * 1536 + n]; off = 0;
    } else if (mat == 1) {     // ktc: N=512 K=256 (wkt | wkc)
        if (idx >= 131072) return;
        int n = idx >> 8, k = idx & 255;
        v = (k < 128) ? wkt[(size_t)l * 65536 + (size_t)k * 512 + n]
                      : wkc[(size_t)l * 65536 + (size_t)(k - 128) * 512 + n];
        off = 196608;
    } else if (mat == 2) {     // wo: N=128 K=512
        if (idx >= 65536) return;
        int n = idx >> 9, k = idx & 511;
        v = wo[(size_t)l * 65536 + (size_t)k * 128 + n]; off = 327680;
    } else if (mat == 3) {     // w1: N=512 K=128
        if (idx >= 65536) return;
        int n = idx >> 7, k = idx & 127;
        v = w1[(size_t)l * 65536 + (size_t)k * 512 + n]; off = 393216;
    } else {                   // w2: N=128 K=512
        if (idx >= 65536) return;
        int n = idx >> 9, k = idx & 511;
        v = w2[(size_t)l * 65536 + (size_t)k * 128 + n]; off = 458752;
    }
    wT[(size_t)l * 524288 + off + idx] = bf16rnd(v);
}

// ---------------- embed ----------------
__global__ __launch_bounds__(128) void embed_kernel(
    const float* __restrict__ eeg, const float* __restrict__ est, const int* __restrict__ cvi,
    const float* __restrict__ cw, const float* __restrict__ cb,
    const float* __restrict__ cls, const float* __restrict__ clsp,
    float* __restrict__ x, ushort* __restrict__ rt, ushort* __restrict__ rc)
{
    int id = blockIdx.x;
    int d = threadIdx.x;
    if (id >= 4096) {
        int b = id - 4096;
        size_t base = (size_t)b * NTOK * 128 + d;
        x[base]  = cls[d];
        rt[base] = bf16rnd(clsp[d]);
        rc[base] = bf16rnd(clsp[d]);
        return;
    }
    int b = id >> 11, rem = id & 2047, c = rem >> 5, w = rem & 31;
    __shared__ float xs[25];
    if (d < 25) xs[d] = eeg[((size_t)(b * CH + c)) * 800 + w * 25 + d];
    __syncthreads();
    float acc = cb[d];
    #pragma unroll
    for (int p = 0; p < 25; ++p) acc += xs[p] * cw[d * 25 + p];
    int i = 1 + c * 32 + w;
    size_t base = ((size_t)b * NTOK + i) * 128 + d;
    x[base] = acc;
    int k = d & 63;
    float invk = __expf(-0.14391156831f * (float)k);
    float pt = floorf(est[b] / 0.1f) + (float)w;
    float at = pt * invk;
    rt[base] = bf16rnd((d < 64) ? sinf(at) : cosf(at));
    float pc = (float)cvi[b * CH + c];
    float ac = pc * invk;
    rc[base] = bf16rnd((d < 64) ? sinf(ac) : cosf(ac));
}

// ---------------- layernorm, bf16 out ----------------
__global__ __launch_bounds__(256) void ln_kernel(
    const float* __restrict__ x, const float* __restrict__ g, const float* __restrict__ bb,
    ushort* __restrict__ out, int rows)
{
    int w = threadIdx.x >> 6, lane = threadIdx.x & 63;
    int row = blockIdx.x * 4 + w;
    if (row >= rows) return;
    const float* xr = x + (size_t)row * 128;
    float v0 = xr[lane], v1 = xr[lane + 64];
    float mean = wave_allreduce_sum(v0 + v1) * (1.0f / 128.0f);
    float d0 = v0 - mean, d1 = v1 - mean;
    float var = wave_allreduce_sum(d0 * d0 + d1 * d1) * (1.0f / 128.0f);
    float inv = rsqrtf(var + 1e-5f);
    out[(size_t)row * 128 + lane]      = bf16rnd(d0 * inv * g[lane]      + bb[lane]);
    out[(size_t)row * 128 + lane + 64] = bf16rnd(d1 * inv * g[lane + 64] + bb[lane + 64]);
}

// ---------------- fused qkv+ktc bf16 MFMA GEMM (one dispatch, 528 blocks) ----------------
// blockIdx.x < 12: C=qkvb = xnb[Mx128] @ wT_qkv[1536x128]^T      (N=1536, K=128)
// blockIdx.x >=12: C=ktcb = (rtb|rcb)[Mx256] @ wT_ktc[512x256]^T (N=512,  K=256)
__global__ __launch_bounds__(256, 3) void mgemm2_kernel(
    const ushort* __restrict__ xnb, const ushort* __restrict__ rtb, const ushort* __restrict__ rcb,
    const ushort* __restrict__ wTl, ushort* __restrict__ qkvb, ushort* __restrict__ ktcb, int M)
{
    __shared__ ushort Alds[128 * 72];
    __shared__ ushort Blds[128 * 72];
    const bool isq = (blockIdx.x < 12);
    const ushort* A  = isq ? xnb : rtb;
    const ushort* A2 = isq ? xnb : rcb;
    const ushort* Wt = isq ? wTl : (wTl + 196608);
    ushort* outB = isq ? qkvb : ktcb;
    const int K1 = 128;
    const int K  = isq ? 128 : 256;
    const int N  = isq ? 1536 : 512;
    const int n0 = (isq ? blockIdx.x : (blockIdx.x - 12)) * 128;
    const int K2s = K - K1;

    int tid = threadIdx.x;
    int lane = tid & 63, wv = tid >> 6;
    int wm = wv >> 1, wn = wv & 1;
    int li = lane & 15, g = lane >> 4;
    int m0 = blockIdx.y * 128;
    f32x4 acc[4][4];
    #pragma unroll
    for (int a = 0; a < 4; ++a)
        #pragma unroll
        for (int c = 0; c < 4; ++c) acc[a][c] = (f32x4){0.f, 0.f, 0.f, 0.f};

    for (int kb = 0; kb < K; kb += 64) {
        #pragma unroll
        for (int it = 0; it < 4; ++it) {
            int gi = tid + it * 256;
            int row = gi >> 3, gc = gi & 7;
            int m = m0 + row; if (m >= M) m = M - 1;
            int acol = kb + gc * 8;
            const ushort* asrc = (acol < K1) ? (A + (size_t)m * K1 + acol)
                                             : (A2 + (size_t)m * K2s + (acol - K1));
            bf16x8 av = *(const bf16x8*)asrc;
            *(bf16x8*)&Alds[row * 72 + ((gc ^ (row & 7)) << 3)] = av;
            int n = n0 + row;
            bf16x8 bv = *(const bf16x8*)(Wt + (size_t)n * K + acol);
            *(bf16x8*)&Blds[row * 72 + ((gc ^ (row & 7)) << 3)] = bv;
        }
        __syncthreads();
        #pragma unroll
        for (int k2 = 0; k2 < 2; ++k2) {
            bf16x8 af[4], bfr[4];
            #pragma unroll
            for (int xx = 0; xx < 4; ++xx) {
                int ra = wm * 64 + xx * 16 + li;
                int rb = wn * 64 + xx * 16 + li;
                af[xx]  = *(const bf16x8*)&Alds[ra * 72 + (((k2 * 4 + g) ^ (ra & 7)) << 3)];
                bfr[xx] = *(const bf16x8*)&Blds[rb * 72 + (((k2 * 4 + g) ^ (rb & 7)) << 3)];
            }
            #pragma unroll
            for (int mi = 0; mi < 4; ++mi)
                #pragma unroll
                for (int ni = 0; ni < 4; ++ni)
                    acc[mi][ni] = __builtin_amdgcn_mfma_f32_16x16x32_bf16(af[mi], bfr[ni], acc[mi][ni], 0, 0, 0);
        }
        __syncthreads();
    }
    #pragma unroll
    for (int mi = 0; mi < 4; ++mi) {
        #pragma unroll
        for (int r = 0; r < 4; ++r) {
            int m = m0 + wm * 64 + mi * 16 + 4 * g + r;
            if (m >= M) continue;
            #pragma unroll
            for (int ni = 0; ni < 4; ++ni) {
                int n = n0 + wn * 64 + ni * 16 + li;
                outB[(size_t)m * N + n] = bf16rnd(acc[mi][ni][r]);
            }
        }
    }
}

// ---------------- bf16 MFMA GEMM (ffn w1, gelu): C = A[MxK] * Wt[NxK] ----------------
__global__ __launch_bounds__(256, 3) void mgemm_kernel(
    const ushort* __restrict__ A, const ushort* __restrict__ Wt,
    ushort* outB, const float* bias, int M, int K, int N)
{
    __shared__ ushort Alds[128 * 72];
    __shared__ ushort Blds[128 * 72];
    int tid = threadIdx.x;
    int lane = tid & 63, wv = tid >> 6;
    int wm = wv >> 1, wn = wv & 1;
    int li = lane & 15, g = lane >> 4;
    int m0 = blockIdx.y * 128, n0 = blockIdx.x * 128;
    f32x4 acc[4][4];
    #pragma unroll
    for (int a = 0; a < 4; ++a)
        #pragma unroll
        for (int c = 0; c < 4; ++c) acc[a][c] = (f32x4){0.f, 0.f, 0.f, 0.f};

    for (int kb = 0; kb < K; kb += 64) {
        #pragma unroll
        for (int it = 0; it < 4; ++it) {
            int gi = tid + it * 256;
            int row = gi >> 3, gc = gi & 7;
            int m = m0 + row; if (m >= M) m = M - 1;
            int acol = kb + gc * 8;
            bf16x8 av = *(const bf16x8*)(A + (size_t)m * K + acol);
            *(bf16x8*)&Alds[row * 72 + ((gc ^ (row & 7)) << 3)] = av;
            int n = n0 + row;
            bf16x8 bv = *(const bf16x8*)(Wt + (size_t)n * K + acol);
            *(bf16x8*)&Blds[row * 72 + ((gc ^ (row & 7)) << 3)] = bv;
        }
        __syncthreads();
        #pragma unroll
        for (int k2 = 0; k2 < 2; ++k2) {
            bf16x8 af[4], bfr[4];
            #pragma unroll
            for (int xx = 0; xx < 4; ++xx) {
                int ra = wm * 64 + xx * 16 + li;
                int rb = wn * 64 + xx * 16 + li;
                af[xx]  = *(const bf16x8*)&Alds[ra * 72 + (((k2 * 4 + g) ^ (ra & 7)) << 3)];
                bfr[xx] = *(const bf16x8*)&Blds[rb * 72 + (((k2 * 4 + g) ^ (rb & 7)) << 3)];
            }
            #pragma unroll
            for (int mi = 0; mi < 4; ++mi)
                #pragma unroll
                for (int ni = 0; ni < 4; ++ni)
                    acc[mi][ni] = __builtin_amdgcn_mfma_f32_16x16x32_bf16(af[mi], bfr[ni], acc[mi][ni], 0, 0, 0);
        }
        __syncthreads();
    }
    #pragma unroll
    for (int mi = 0; mi < 4; ++mi) {
        #pragma unroll
        for (int r = 0; r < 4; ++r) {
            int m = m0 + wm * 64 + mi * 16 + 4 * g + r;
            if (m >= M) continue;
            #pragma unroll
            for (int ni = 0; ni < 4; ++ni) {
                int n = n0 + wn * 64 + ni * 16 + li;
                float v = acc[mi][ni][r] + bias[n];
                v = 0.5f * v * (1.0f + erff(v * 0.70710678118f));
                outB[(size_t)m * N + n] = bf16rnd(v);
            }
        }
    }
}

// ---------------- thin GEMM (N=128, K=512): 2 n-tiles per wave (ILP), no LDS ----------------
__global__ __launch_bounds__(256) void tgemm_kernel(
    const ushort* __restrict__ A, const ushort* __restrict__ Wt,
    float* __restrict__ outF, const float* __restrict__ bias, const float* __restrict__ res,
    int M, int N)
{
    int lane = threadIdx.x & 63, wv = threadIdx.x >> 6;
    int li = lane & 15, g = lane >> 4;
    int mt = blockIdx.y * 4 + wv;
    int m0 = mt * 16, n0 = blockIdx.x * 32;
    int ar = m0 + li; if (ar >= M) ar = M - 1;
    const ushort* arow  = A + (size_t)ar * 512 + 8 * g;
    const ushort* brow0 = Wt + (size_t)(n0 + li) * 512 + 8 * g;
    const ushort* brow1 = Wt + (size_t)(n0 + 16 + li) * 512 + 8 * g;
    f32x4 acc0 = (f32x4){0.f, 0.f, 0.f, 0.f};
    f32x4 acc1 = (f32x4){0.f, 0.f, 0.f, 0.f};
    #pragma unroll
    for (int k2 = 0; k2 < 16; ++k2) {
        bf16x8 af  = *(const bf16x8*)(arow + k2 * 32);
        bf16x8 bf0 = *(const bf16x8*)(brow0 + k2 * 32);
        bf16x8 bf1 = *(const bf16x8*)(brow1 + k2 * 32);
        acc0 = __builtin_amdgcn_mfma_f32_16x16x32_bf16(af, bf0, acc0, 0, 0, 0);
        acc1 = __builtin_amdgcn_mfma_f32_16x16x32_bf16(af, bf1, acc1, 0, 0, 0);
    }
    #pragma unroll
    for (int r = 0; r < 4; ++r) {
        int m = m0 + 4 * g + r;
        if (m < M) {
            int n = n0 + li;
            outF[(size_t)m * N + n]      = acc0[r] + bias[n]      + res[(size_t)m * N + n];
            outF[(size_t)m * N + n + 16] = acc1[r] + bias[n + 16] + res[(size_t)m * N + n + 16];
        }
    }
}

// ---------------- fused prep: remap (ksum/colb) + vtrans (vt), one dispatch ----------------
// blocks [0, MROWS+30): remap role (512 thr); blocks [MROWS+30, +1040): vtrans role
// (512 thr = 2x 256-thr dt-tiles).
__global__ __launch_bounds__(512) void prep_kernel(
    const ushort* __restrict__ qkvb, const ushort* __restrict__ ktcb,
    const float* __restrict__ bte, const float* __restrict__ btr,
    const float* __restrict__ bcr, const float* __restrict__ bce,
    ushort* __restrict__ ksum, float* __restrict__ colb, ushort* __restrict__ vt)
{
    __shared__ ushort tile[2][32][36];
    int id = blockIdx.x;
    int t512 = threadIdx.x;
    if (id < MROWS + 30) {
        // ---- remap role ----
        if (id >= MROWS) {          // zero pad rows j in [2049,2064)
            int pidx = id - MROWS;
            int b2 = pidx / 15, i2 = 2049 + pidx % 15;
            ksum[((size_t)(b2 * NTOKP + i2)) * 512 + t512] = 0;
            if (t512 < 8) colb[((size_t)(b2 * NTOKP + i2)) * 8 + t512] = 0.0f;
            return;
        }
        int b2 = id / NTOK, i2 = id - b2 * NTOK;
        int h2 = t512 >> 6, d2 = t512 & 63;
        int G = i2 * 16 + b2 * 8 + h2;
        int bhA = G / 2049, iA = G - bhA * 2049;
        int bA = bhA >> 3, hA = bhA & 7;
        size_t qbase = ((size_t)(bA * NTOK + iA)) * 1536 + hA * 64 + d2;
        ushort kvu = qkvb[qbase + 512];
        int bB = G / 16392, remB = G - bB * 16392;
        int iB = remB >> 3, hB = remB & 7;
        ushort ktcu = ktcb[((size_t)(bB * NTOK + iB)) * 512 + hB * 64 + d2];
        float kv = bf16tof(kvu), ktcv = bf16tof(ktcu);
        ksum[((size_t)(b2 * NTOKP + i2)) * 512 + t512] = bf16rnd((kv + ktcv) * QSCALE);
        float cbx = (bte[t512] + bce[t512]) * kv + (btr[t512] + bcr[t512]) * ktcv;
        cbx = wave_allreduce_sum(cbx);
        if (d2 == 0) colb[((size_t)(b2 * NTOKP + i2)) * 8 + h2] = cbx;
        return;
    }
    // ---- vtrans role ----
    int vid = id - (MROWS + 30);
    int jt = vid % 65;
    int rest = vid / 65;       // 0..15
    int dt2 = rest & 7, b = rest >> 3;
    int half = t512 >> 8;      // which dt of the pair
    int t = t512 & 255;
    int dt = dt2 * 2 + half;
    {
        int jj = t >> 3, dq = t & 7;
        int j = jt * 32 + jj;
        ushort4 v = make_ushort4(0, 0, 0, 0);
        if (j <= 2048) {
            int h2 = dt >> 1;
            int d2 = (dt & 1) * 32 + dq * 4;
            int G = j * 16 + b * 8 + h2;
            int bhA = G / 2049, iA = G - bhA * 2049;
            int bA = bhA >> 3, hA = bhA & 7;
            v = *(const ushort4*)(qkvb + ((size_t)(bA * NTOK + iA)) * 1536 + 1024 + hA * 64 + d2);
        }
        *(ushort4*)&tile[half][jj][dq * 4] = v;
    }
    __syncthreads();
    {
        int dd = t >> 3, jq = t & 7;
        ushort4 w;
        w.x = tile[half][jq * 4 + 0][dd];
        w.y = tile[half][jq * 4 + 1][dd];
        w.z = tile[half][jq * 4 + 2][dd];
        w.w = tile[half][jq * 4 + 3][dd];
        *(ushort4*)(vt + ((size_t)b * 512 + dt * 32 + dd) * 2080 + jt * 32 + jq * 4) = w;
    }
}

// ---------------- attn9: swapped-QK, heads split across wave pair + LDS sum-exchange ----------------
// Best-measured structure (85 us/layer). grid (65, NCJ=3, 2) = 390 blocks, 2 blocks/CU.
// Everything double-buffered; K/V/cb staged post-B2 (one full iteration of prefetch distance).
// LDS: K dbuf 2x16K @0 | V dbuf 2x16K @32768 | cb dbuf 2x768 @65536 | ex 4K @67072 = 69.4KB.
__global__ __launch_bounds__(256, 2) void attn9_kernel(
    const ushort* __restrict__ qkvb, const ushort* __restrict__ ks,
    const ushort* __restrict__ vt, const float* __restrict__ colb,
    ushort* __restrict__ Op)
{
    __shared__ __align__(16) char smem[71168];
    const int tid = threadIdx.x;
    const int lane = tid & 63, wv = tid >> 6;
    const int wi = wv >> 1, hg = wv & 1;
    const int g = lane >> 4, li = lane & 15;
    const int nc = blockIdx.y, b = blockIdx.z;
    const int i0 = blockIdx.x * 32;
    const int jt0 = nc * 43, jt1 = (nc + 1) * 43;

    // Q fragments: own 4 heads x 2 k2, gathered from qkvb (old space) via inverse map
    bf16x8 qf[4][2];
    {
        int iq = i0 + wi * 16 + li; if (iq > 2048) iq = 2048;
        #pragma unroll
        for (int hh = 0; hh < 4; ++hh) {
            int h2 = hg * 4 + hh;
            int G = iq * 16 + b * 8 + h2;
            int bhA = G / 2049, iA = G - bhA * 2049;
            int bA = bhA >> 3, hA = bhA & 7;
            const ushort* qrow = qkvb + ((size_t)(bA * NTOK + iA)) * 1536 + hA * 64 + 8 * g;
            qf[hh][0] = *(const bf16x8*)(qrow);
            qf[hh][1] = *(const bf16x8*)(qrow + 32);
        }
    }
    f32x4 o[4][4];   // own 4 heads x 4 d-subtiles -> AGPR
    #pragma unroll
    for (int a = 0; a < 4; ++a)
        #pragma unroll
        for (int m = 0; m < 4; ++m) o[a][m] = (f32x4){0.f, 0.f, 0.f, 0.f};

    // hoisted per-lane LDS read bases
    const unsigned koff0 = (unsigned)(li * 1024) + (unsigned)((g * 16) ^ ((li & 7) << 4))
                         + (unsigned)(hg * 512);
    const unsigned koff1 = (unsigned)(li * 1024) + (unsigned)((64 + g * 16) ^ ((li & 7) << 4))
                         + (unsigned)(hg * 512);
    const unsigned vboff = (unsigned)(li * 32)
                         + (unsigned)((((g >> 1) ^ ((li >> 2) & 1)) << 4) + (g & 1) * 8)
                         + (unsigned)(hg * 8192);
    const unsigned exoff = 67072u + (unsigned)(wv * 1024 + lane * 16);
    const unsigned exoffp = 67072u + (unsigned)((wv ^ 1) * 1024 + lane * 16);

    // staging (padded buffers: NO clamps, affine in jt)
    const ushort* ksb_b = ks + ((size_t)b * NTOKP) * 512;
    auto stageK = [&](int jt, int buf) {
        #pragma unroll
        for (int t = 0; t < 4; ++t) {
            unsigned L = (unsigned)((wv * 256 + t * 64 + lane) * 16);
            unsigned Lp = L ^ (((L >> 10) & 7u) << 4);
            const ushort* src = ksb_b + (size_t)(jt * 16 + (int)(Lp >> 10)) * 512 + ((Lp & 1023u) >> 1);
            GLOAD_LDS16(src, smem + buf * 16384 + (wv * 256 + t * 64) * 16);
        }
    };
    const ushort* vtb_b = vt + (size_t)b * 512 * 2080;
    auto stageV = [&](int jt, int buf) {
        #pragma unroll
        for (int t = 0; t < 4; ++t) {
            int n = wv * 256 + t * 64 + lane;
            int d = n >> 1;
            int h16 = (n & 1) ^ ((n >> 3) & 1);
            const ushort* src = vtb_b + (size_t)d * 2080 + jt * 16 + h16 * 8;
            GLOAD_LDS16(src, smem + 32768 + buf * 16384 + (wv * 256 + t * 64) * 16);
        }
    };
    auto loadcb = [&](int jt) -> float {
        if (tid < 128) {
            int jg = jt * 16 + (tid >> 3);
            if (jg > 2063) jg = 2063;      // pad rows are zero; just keep in-bounds
            return colb[((size_t)(b * NTOKP + jg)) * 8 + (tid & 7)] * QSCALE;
        }
        return 0.f;
    };

    stageK(jt0, 0); stageV(jt0, 0);
    {
        float c0 = loadcb(jt0);
        if (tid < 128) ((float*)(smem + 65536))[(tid >> 3) * 12 + (tid & 7)] = c0;
    }
    float cbreg = loadcb(jt0 + 1);

    int cur = 0;
    for (int jt = jt0; jt < jt1; ++jt) {
        __syncthreads();   // B1: staging(jt)+cb(jt) visible; prev ex reads done
        // ---- QK (swapped): s[hh](j=4g+r, i=li), own 4 heads only ----
        const char* kb = smem + cur * 16384;
        f32x4 s[4];
        #pragma unroll
        for (int hh = 0; hh < 4; ++hh) {
            s[hh] = (f32x4){0.f, 0.f, 0.f, 0.f};
            bf16x8 kf0 = *(const bf16x8*)(kb + koff0 + hh * 128);
            s[hh] = __builtin_amdgcn_mfma_f32_16x16x32_bf16(kf0, qf[hh][0], s[hh], 0, 0, 0);
            bf16x8 kf1 = *(const bf16x8*)(kb + koff1 + hh * 128);
            s[hh] = __builtin_amdgcn_mfma_f32_16x16x32_bf16(kf1, qf[hh][1], s[hh], 0, 0, 0);
        }
        // ---- exp2 own heads + partial head-sum -> LDS exchange ----
        const float* cbl = (const float*)(smem + 65536 + cur * 768);
        float p[4][4];
        #pragma unroll
        for (int rp = 0; rp < 2; ++rp) {
            f32x4 ce = *(const f32x4*)(cbl + (4 * g + 2 * rp) * 12 + hg * 4);
            f32x4 co = *(const f32x4*)(cbl + (4 * g + 2 * rp) * 12 + 12 + hg * 4);
            #pragma unroll
            for (int hh = 0; hh < 4; ++hh) {
                p[hh][2 * rp]     = __builtin_amdgcn_exp2f(s[hh][2 * rp]     + ce[hh]);
                p[hh][2 * rp + 1] = __builtin_amdgcn_exp2f(s[hh][2 * rp + 1] + co[hh]);
            }
        }
        f32x4 e;
        #pragma unroll
        for (int r = 0; r < 4; ++r)
            e[r] = (p[0][r] + p[1][r]) + (p[2][r] + p[3][r]);
        *(f32x4*)(smem + exoff) = e;
        __syncthreads();   // B2: exchange visible (staging(jt) long drained)
        f32x4 eo = *(const f32x4*)(smem + exoffp);
        // ---- issue next-tile staging + cb write NOW (post-B2: latency spans PV + next QK) ----
        const bool hn = (jt + 1 < jt1);
        if (hn) {
            if (tid < 128) ((float*)(smem + 65536 + (cur ^ 1) * 768))[(tid >> 3) * 12 + (tid & 7)] = cbreg;
            stageK(jt + 1, cur ^ 1);
            stageV(jt + 1, cur ^ 1);
            cbreg = loadcb(jt + 2);
        }
        // ---- full softmax denominator, pack P (PV A-operand) ----
        float inv[4];
        #pragma unroll
        for (int r = 0; r < 4; ++r)
            inv[r] = __builtin_amdgcn_rcpf(fmaxf(e[r] + eo[r], 1e-20f));  // NORMAL floor
        unsigned P2[4][2];
        #pragma unroll
        for (int hh = 0; hh < 4; ++hh)
            #pragma unroll
            for (int rp = 0; rp < 2; ++rp) {
                float lo = p[hh][2 * rp] * inv[2 * rp];
                float hi = p[hh][2 * rp + 1] * inv[2 * rp + 1];
                asm("v_cvt_pk_bf16_f32 %0, %1, %2" : "=v"(P2[hh][rp]) : "v"(lo), "v"(hi));
            }
        // ---- PV: own 4 heads, 16x16x16, o in AGPR ----
        const char* vb = smem + 32768 + cur * 16384 + vboff;
        #pragma unroll
        for (int hh = 0; hh < 4; ++hh) {
            i32x2 pa = (i32x2){(int)P2[hh][0], (int)P2[hh][1]};
            #pragma unroll
            for (int dt = 0; dt < 4; ++dt) {
                i32x2 vv = *(const i32x2*)(vb + hh * 2048 + dt * 512);
                asm("v_mfma_f32_16x16x16_bf16 %0, %1, %2, %0"
                    : "+a"(o[hh][dt]) : "v"(pa), "v"(vv));
            }
        }
        cur ^= 1;
    }
    // ---- store partial O (bf16): i = i0+wi*16+4g+r, d = (hg*4+hh)*64 + dt*16 + li ----
    {
        int irow0 = i0 + wi * 16 + 4 * g;
        #pragma unroll
        for (int hh = 0; hh < 4; ++hh) {
            int d0 = (hg * 4 + hh) * 64;
            #pragma unroll
            for (int dt = 0; dt < 4; ++dt) {
                #pragma unroll
                for (int r = 0; r < 4; ++r) {
                    int irow = irow0 + r;
                    if (irow <= 2048) {
                        Op[(((size_t)(nc * 2 + b)) * 2049 + irow) * 512 + d0 + dt * 16 + li] =
                            bf16rnd(o[hh][dt][r]);
                    }
                }
            }
        }
    }
}

// ---------------- sum NCJ bf16 partials -> bf16 attno ----------------
__global__ __launch_bounds__(256) void osum_kernel(
    const ushort* __restrict__ Op, ushort* __restrict__ attno)
{
    int idx = blockIdx.x * 256 + threadIdx.x;
    if (idx >= MROWS * 64) return;
    int row = idx >> 6, dq = idx & 63;
    int b = row / NTOK, i = row - b * NTOK;
    float acc[8];
    #pragma unroll
    for (int e = 0; e < 8; ++e) acc[e] = 0.f;
    #pragma unroll
    for (int nc = 0; nc < NCJ; ++nc) {
        const ushort* src = Op + (((size_t)(nc * 2 + b)) * 2049 + i) * 512 + dq * 8;
        int4 v = *(const int4*)src;
        const ushort* up = (const ushort*)&v;
        #pragma unroll
        for (int e = 0; e < 8; ++e) acc[e] += bf16tof(up[e]);
    }
    ushort ov[8];
    #pragma unroll
    for (int e = 0; e < 8; ++e) ov[e] = bf16rnd(acc[e]);
    *(int4*)(attno + (size_t)row * 512 + dq * 8) = *(int4*)ov;
}

// ---------------- head ----------------
__global__ void head_kernel(
    const float* __restrict__ x, const float* __restrict__ g, const float* __restrict__ b,
    const float* __restrict__ w, const float* __restrict__ hb, float* __restrict__ out)
{
    int lane = threadIdx.x & 63;
    for (int bi = 0; bi < 2; ++bi) {
        const float* xr = x + (size_t)bi * NTOK * 128;
        float v0 = xr[lane], v1 = xr[lane + 64];
        float mean = wave_allreduce_sum(v0 + v1) * (1.0f / 128.0f);
        float d0 = v0 - mean, d1 = v1 - mean;
        float var = wave_allreduce_sum(d0 * d0 + d1 * d1) * (1.0f / 128.0f);
        float inv = rsqrtf(var + 1e-5f);
        float y0 = d0 * inv * g[lane] + b[lane];
        float y1 = d1 * inv * g[lane + 64] + b[lane + 64];
        for (int c = 0; c < 4; ++c) {
            float pt = y0 * w[lane * 4 + c] + y1 * w[(lane + 64) * 4 + c];
            pt = wave_allreduce_sum(pt);
            if (lane == 0) out[bi * 4 + c] = pt + hb[c];
        }
    }
}

extern "C" void kernel_launch(void* const* d_in, const int* in_sizes, int n_in,
                              void* d_out, int out_size, void* d_ws, size_t ws_size,
                              hipStream_t stream) {
    const float* eeg   = (const float*)d_in[0];
    const float* est   = (const float*)d_in[1];
    const int*   cvi   = (const int*)d_in[2];
    const float* convw = (const float*)d_in[3];
    const float* convb = (const float*)d_in[4];
    const float* cls   = (const float*)d_in[5];
    const float* clsp  = (const float*)d_in[6];
    const float* bte   = (const float*)d_in[7];
    const float* btr   = (const float*)d_in[8];
    const float* bcr   = (const float*)d_in[9];
    const float* bce   = (const float*)d_in[10];
    const float* ln1g  = (const float*)d_in[11];
    const float* ln1b  = (const float*)d_in[12];
    const float* wqkv  = (const float*)d_in[13];
    const float* wkt   = (const float*)d_in[14];
    const float* wkc   = (const float*)d_in[15];
    const float* wo    = (const float*)d_in[16];
    const float* bo    = (const float*)d_in[17];
    const float* ln2g  = (const float*)d_in[18];
    const float* ln2b  = (const float*)d_in[19];
    const float* w1    = (const float*)d_in[20];
    const float* b1    = (const float*)d_in[21];
    const float* w2    = (const float*)d_in[22];
    const float* b2    = (const float*)d_in[23];
    const float* hlng  = (const float*)d_in[24];
    const float* hlnb  = (const float*)d_in[25];
    const float* hw    = (const float*)d_in[26];
    const float* hb    = (const float*)d_in[27];

    float* ws    = (float*)d_ws;
    float* x_    = ws + OFF_X;
    ushort* xnb  = (ushort*)(ws + OFF_XNB);
    ushort* rtb  = (ushort*)(ws + OFF_RTB);
    ushort* rcb  = (ushort*)(ws + OFF_RCB);
    ushort* qkvb = (ushort*)(ws + OFF_QKVB);
    ushort* ktcb = (ushort*)(ws + OFF_KTCB);
    ushort* ksb  = (ushort*)(ws + OFF_KSB);
    ushort* vtb  = (ushort*)(ws + OFF_VTB);
    float* colb_ = ws + OFF_COLB;
    ushort* wT   = (ushort*)(ws + OFF_WT);
    ushort* opb  = (ushort*)(ws + OFF_OP);
    ushort* attnob = (ushort*)(ws + OFF_ATTNO);
    ushort* ffnhb  = (ushort*)(ws + OFF_FFNH);

    wprep_kernel<<<dim3(768, 5, 2), 256, 0, stream>>>(wqkv, wkt, wkc, wo, w1, w2, wT);
    embed_kernel<<<4098, 128, 0, stream>>>(eeg, est, cvi, convw, convb, cls, clsp, x_, rtb, rcb);

    for (int l = 0; l < 2; ++l) {
        const ushort* wTl = wT + (size_t)l * 524288;
        ln_kernel<<<1025, 256, 0, stream>>>(x_, ln1g + l * 128, ln1b + l * 128, xnb, MROWS);
        mgemm2_kernel<<<dim3(16, 33), 256, 0, stream>>>(xnb, rtb, rcb, wTl, qkvb, ktcb, MROWS);
        prep_kernel<<<MROWS + 30 + 1040, 512, 0, stream>>>(qkvb, ktcb, bte, btr, bcr, bce,
                                                           ksb, colb_, vtb);
        attn9_kernel<<<dim3(65, NCJ, 2), 256, 0, stream>>>(qkvb, ksb, vtb, colb_, opb);
        osum_kernel<<<1025, 256, 0, stream>>>(opb, attnob);
        tgemm_kernel<<<dim3(4, 65), 256, 0, stream>>>(attnob, wTl + 327680, x_,
                                                      bo + l * 128, x_, MROWS, 128);
        ln_kernel<<<1025, 256, 0, stream>>>(x_, ln2g + l * 128, ln2b + l * 128, xnb, MROWS);
        mgemm_kernel<<<dim3(4, 33), 256, 0, stream>>>(xnb, wTl + 393216, ffnhb,
                                                      b1 + l * 512, MROWS, 128, 512);
        tgemm_kernel<<<dim3(4, 65), 256, 0, stream>>>(ffnhb, wTl + 458752, x_,
                                                      b2 + l * 128, x_, MROWS, 128);
    }
    head_kernel<<<1, 64, 0, stream>>>(x_, hlng, hlnb, hw, hb, (float*)d_out);
}